// Round 1
// baseline (7416.822 us; speedup 1.0000x reference)
//
#include <hip/hip_runtime.h>
#include <cstdint>
#include <cstddef>

#define B_  2
#define S_  2048
#define D_  4096
#define QH_ 32
#define NH_ 8
#define HD_ 128

typedef __attribute__((ext_vector_type(8))) short bf16x8;
typedef __attribute__((ext_vector_type(4))) float f32x4;

__device__ __forceinline__ unsigned short f2bf(float f) {
    unsigned int u = __float_as_uint(f);
    return (unsigned short)((u + 0x7FFFu + ((u >> 16) & 1u)) >> 16);
}
__device__ __forceinline__ float bf2f(unsigned short h) { return __uint_as_float(((unsigned int)h) << 16); }
__device__ __forceinline__ float bflo(unsigned int u)   { return __uint_as_float(u << 16); }
__device__ __forceinline__ float bfhi(unsigned int u)   { return __uint_as_float(u & 0xffff0000u); }

// ---------------------------------------------------------------------------
// GEMM: C[M,N] = A[M,K] * B[K,N]
//   BMODE 0: B is head-blocked QKV weight W[head][k][h] (head = n>>7, h = n&127)
//   BMODE 1: B is plain row-major [K][N]
//   ABF: A is bf16 (ushort) else fp32 (converted during staging)
//   CF32: C written fp32 else bf16
// 128x128 tile, BK=64, 4 waves (2x2), 16x16x32 bf16 MFMA, single-buffered.
// ---------------------------------------------------------------------------
template<int BMODE, int ABF, int CF32>
__global__ __launch_bounds__(256)
void gemm_kernel(const void* __restrict__ Ap, const float* __restrict__ Bp,
                 void* __restrict__ Cp, int M, int N, int K)
{
    constexpr int BM = 128, BN = 128, BK = 64, LDP = 72; // pad 64->72: 2-way-free frags
    __shared__ alignas(16) unsigned short As[BM][LDP];
    __shared__ alignas(16) unsigned short Bs[BN][LDP];   // stored [n][k]

    const int t  = threadIdx.x;
    const int bn = blockIdx.x * BN;
    const int bm = blockIdx.y * BM;
    const int l  = t & 63, w = t >> 6;
    const int wr = w >> 1, wc = w & 1;
    const int lm = l & 15;
    const int lko = (l >> 4) * 8;

    f32x4 acc[4][4];
    const f32x4 zero = {0.f, 0.f, 0.f, 0.f};
    #pragma unroll
    for (int i = 0; i < 4; ++i)
        #pragma unroll
        for (int j = 0; j < 4; ++j) acc[i][j] = zero;

    const int nkt = K / BK;
    for (int kt = 0; kt < nkt; ++kt) {
        __syncthreads();
        // ---- stage A tile -> As[m][k] (bf16) ----
        if constexpr (ABF) {
            const unsigned short* A = (const unsigned short*)Ap;
            #pragma unroll
            for (int p = 0; p < 4; ++p) {
                int m  = p * 32 + (t >> 3);
                int k0 = (t & 7) * 8;
                uint4 v = *(const uint4*)(A + (size_t)(bm + m) * K + kt * BK + k0);
                *(uint4*)&As[m][k0] = v;
            }
        } else {
            const float* A = (const float*)Ap;
            #pragma unroll
            for (int p = 0; p < 8; ++p) {
                int m  = p * 16 + (t >> 4);
                int k0 = (t & 15) * 4;
                float4 v = *(const float4*)(A + (size_t)(bm + m) * K + kt * BK + k0);
                unsigned int lo = (unsigned int)f2bf(v.x) | ((unsigned int)f2bf(v.y) << 16);
                unsigned int hi = (unsigned int)f2bf(v.z) | ((unsigned int)f2bf(v.w) << 16);
                *(uint2*)&As[m][k0] = make_uint2(lo, hi);
            }
        }
        // ---- stage B tile -> Bs[n][k] (bf16, transposed in LDS) ----
        #pragma unroll
        for (int p = 0; p < 8; ++p) {
            int kk = p * 8 + (t >> 5);
            int n0 = (t & 31) * 4;
            size_t off;
            if constexpr (BMODE == 0)
                off = (size_t)(bn >> 7) * ((size_t)D_ * HD_) + (size_t)(kt * BK + kk) * HD_ + n0;
            else
                off = (size_t)(kt * BK + kk) * N + bn + n0;
            float4 v = *(const float4*)(Bp + off);
            Bs[n0 + 0][kk] = f2bf(v.x);
            Bs[n0 + 1][kk] = f2bf(v.y);
            Bs[n0 + 2][kk] = f2bf(v.z);
            Bs[n0 + 3][kk] = f2bf(v.w);
        }
        __syncthreads();
        // ---- MFMA on the tile ----
        #pragma unroll
        for (int kk = 0; kk < BK; kk += 32) {
            bf16x8 af[4], bfv[4];
            #pragma unroll
            for (int i = 0; i < 4; ++i) af[i]  = *(const bf16x8*)&As[wr * 64 + i * 16 + lm][kk + lko];
            #pragma unroll
            for (int j = 0; j < 4; ++j) bfv[j] = *(const bf16x8*)&Bs[wc * 64 + j * 16 + lm][kk + lko];
            #pragma unroll
            for (int i = 0; i < 4; ++i)
                #pragma unroll
                for (int j = 0; j < 4; ++j)
                    acc[i][j] = __builtin_amdgcn_mfma_f32_16x16x32_bf16(af[i], bfv[j], acc[i][j], 0, 0, 0);
        }
    }
    // ---- C write: col = lane&15, row = (lane>>4)*4 + reg (HW-measured) ----
    const int lr4 = (l >> 4) * 4;
    #pragma unroll
    for (int i = 0; i < 4; ++i) {
        #pragma unroll
        for (int j = 0; j < 4; ++j) {
            int row = bm + wr * 64 + i * 16 + lr4;
            int col = bn + wc * 64 + j * 16 + lm;
            #pragma unroll
            for (int jj = 0; jj < 4; ++jj) {
                if constexpr (CF32)
                    ((float*)Cp)[(size_t)(row + jj) * N + col] = acc[i][j][jj];
                else
                    ((unsigned short*)Cp)[(size_t)(row + jj) * N + col] = f2bf(acc[i][j][jj]);
            }
        }
    }
}

// ---------------------------------------------------------------------------
// RoPE in-place on bf16 [rows][128]; row = (b*S+s)*NHEADS + head
// ---------------------------------------------------------------------------
template<int NHEADS>
__global__ __launch_bounds__(256)
void rope_kernel(unsigned short* __restrict__ data, const int* __restrict__ positions)
{
    const int gid = blockIdx.x * 256 + threadIdx.x;
    const int j   = gid & 63;
    const int row = gid >> 6;
    const int bs  = row / NHEADS;
    const float pos = (float)positions[bs];
    const float inv = expf(-0.14391156831f * (float)j);  // 10000^(-j/64)
    float s, c;
    sincosf(pos * inv, &s, &c);
    const size_t base = (size_t)row * HD_;
    const float x1 = bf2f(data[base + j]);
    const float x2 = bf2f(data[base + 64 + j]);
    data[base + j]      = f2bf(x1 * c - x2 * s);
    data[base + 64 + j] = f2bf(x2 * c + x1 * s);
}

// ---------------------------------------------------------------------------
// Vector flash attention. Block = 256 thr (4 waves), one (b, qh, 64-row block).
// Wave w owns rows w*16..w*16+15; lane owns one key per 64-key chunk.
// ---------------------------------------------------------------------------
__global__ __launch_bounds__(256)
void attn_kernel(const unsigned short* __restrict__ qr,
                 const unsigned short* __restrict__ kr,
                 const unsigned short* __restrict__ vr,
                 unsigned short* __restrict__ ao)
{
    constexpr int LDK = 132; // pad: score reads 4-way, v reads 2-way (free)
    __shared__ alignas(16) unsigned short q_s[64][128];
    __shared__ alignas(16) unsigned short k_s[64][LDK];
    __shared__ alignas(16) unsigned short v_s[64][LDK];
    __shared__ float p_s[4][16][64];

    const int t  = threadIdx.x;
    const int blk = blockIdx.x;
    const int sb = blk & 31;
    const int qh = (blk >> 5) & 31;
    const int b  = blk >> 10;
    const int kh = qh >> 2;
    const int l  = t & 63, w = t >> 6;

    { // stage Q block once
        const int row = t >> 2, seg = t & 3;
        const size_t gq = ((size_t)(b * S_ + sb * 64 + row) * QH_ + qh) * HD_ + seg * 32;
        const uint4* src = (const uint4*)(qr + gq);
        #pragma unroll
        for (int i = 0; i < 4; ++i) *(uint4*)&q_s[row][seg * 32 + i * 8] = src[i];
    }

    float mreg[16], lreg[16], acc0[16], acc1[16];
    #pragma unroll
    for (int r = 0; r < 16; ++r) { mreg[r] = -1e30f; lreg[r] = 0.f; acc0[r] = 0.f; acc1[r] = 0.f; }

    const float sm_scale = 0.08838834764831845f; // 1/sqrt(128)

    for (int c = 0; c <= sb; ++c) {
        __syncthreads(); // previous chunk's PV readers done
        { // stage K/V chunk
            const int key = t >> 2, seg = t & 3;
            const size_t gk = ((size_t)(b * S_ + c * 64 + key) * NH_ + kh) * HD_ + seg * 32;
            const uint4* ksrc = (const uint4*)(kr + gk);
            const uint4* vsrc = (const uint4*)(vr + gk);
            #pragma unroll
            for (int i = 0; i < 4; ++i) {
                uint4 kv = ksrc[i], vv = vsrc[i];
                *(uint2*)&k_s[key][seg * 32 + i * 8]     = make_uint2(kv.x, kv.y);
                *(uint2*)&k_s[key][seg * 32 + i * 8 + 4] = make_uint2(kv.z, kv.w);
                *(uint2*)&v_s[key][seg * 32 + i * 8]     = make_uint2(vv.x, vv.y);
                *(uint2*)&v_s[key][seg * 32 + i * 8 + 4] = make_uint2(vv.z, vv.w);
            }
        }
        __syncthreads();
        const bool diag = (c == sb);
        #pragma unroll 1
        for (int r = 0; r < 16; ++r) {
            const int rl = w * 16 + r;
            float sc = 0.f;
            #pragma unroll 8
            for (int dp = 0; dp < 64; ++dp) {
                unsigned int qb = *(const unsigned int*)&q_s[rl][dp * 2];
                unsigned int kb = *(const unsigned int*)&k_s[l][dp * 2];
                sc += bflo(qb) * bflo(kb);
                sc += bfhi(qb) * bfhi(kb);
            }
            sc *= sm_scale;
            const bool valid = (!diag) || (l <= rl);
            if (!valid) sc = -1e30f;
            float mc = sc;
            #pragma unroll
            for (int off = 32; off; off >>= 1) mc = fmaxf(mc, __shfl_xor(mc, off, 64));
            const float mnew  = fmaxf(mreg[r], mc);
            const float scale = __expf(mreg[r] - mnew);
            const float p  = valid ? __expf(sc - mnew) : 0.f;
            float ps = p;
            #pragma unroll
            for (int off = 32; off; off >>= 1) ps += __shfl_xor(ps, off, 64);
            lreg[r] = lreg[r] * scale + ps;
            mreg[r] = mnew;
            acc0[r] *= scale; acc1[r] *= scale;
            p_s[w][r][l] = p;
        }
        __syncthreads();
        #pragma unroll 1
        for (int r = 0; r < 16; ++r) {
            float a0 = 0.f, a1 = 0.f;
            #pragma unroll 8
            for (int k = 0; k < 64; ++k) {
                const float p = p_s[w][r][k];
                unsigned int vb = *(const unsigned int*)&v_s[k][2 * l];
                a0 += p * bflo(vb);
                a1 += p * bfhi(vb);
            }
            acc0[r] += a0; acc1[r] += a1;
        }
    }
    #pragma unroll 1
    for (int r = 0; r < 16; ++r) {
        const int rl = w * 16 + r;
        const float invl = 1.f / lreg[r];
        unsigned int packed = (unsigned int)f2bf(acc0[r] * invl)
                            | ((unsigned int)f2bf(acc1[r] * invl) << 16);
        const size_t g = ((size_t)(b * S_ + sb * 64 + rl) * QH_ + qh) * (HD_ / 2) + l;
        ((unsigned int*)ao)[g] = packed;
    }
}

// ---------------------------------------------------------------------------
extern "C" void kernel_launch(void* const* d_in, const int* in_sizes, int n_in,
                              void* d_out, int out_size, void* d_ws, size_t ws_size,
                              hipStream_t stream)
{
    const float* x  = (const float*)d_in[0];
    const int*  pos = (const int*)d_in[1];
    const float* Wq = (const float*)d_in[2];
    const float* Wk = (const float*)d_in[3];
    const float* Wv = (const float*)d_in[4];
    const float* Wo = (const float*)d_in[5];
    float* out = (float*)d_out;

    char* wsb = (char*)d_ws;
    unsigned short* q_bf  = (unsigned short*)(wsb);              // 32 MiB
    unsigned short* k_bf  = (unsigned short*)(wsb + 33554432);   //  8 MiB
    unsigned short* v_bf  = (unsigned short*)(wsb + 41943040);   //  8 MiB
    unsigned short* ao_bf = (unsigned short*)(wsb + 50331648);   // 32 MiB

    const dim3 blk(256);
    const int M = B_ * S_;             // 4096
    // QKV projections (x fp32 -> bf16 Q/K/V)
    gemm_kernel<0, 0, 0><<<dim3((QH_ * HD_) / 128, M / 128), blk, 0, stream>>>(
        (const void*)x, Wq, (void*)q_bf, M, QH_ * HD_, D_);
    gemm_kernel<0, 0, 0><<<dim3((NH_ * HD_) / 128, M / 128), blk, 0, stream>>>(
        (const void*)x, Wk, (void*)k_bf, M, NH_ * HD_, D_);
    gemm_kernel<0, 0, 0><<<dim3((NH_ * HD_) / 128, M / 128), blk, 0, stream>>>(
        (const void*)x, Wv, (void*)v_bf, M, NH_ * HD_, D_);
    // RoPE on Q and K
    rope_kernel<QH_><<<(B_ * S_ * QH_ * 64) / 256, blk, 0, stream>>>(q_bf, pos);
    rope_kernel<NH_><<<(B_ * S_ * NH_ * 64) / 256, blk, 0, stream>>>(k_bf, pos);
    // causal GQA attention
    attn_kernel<<<B_ * QH_ * (S_ / 64), blk, 0, stream>>>(q_bf, k_bf, v_bf, ao_bf);
    // output projection -> fp32 d_out
    gemm_kernel<1, 1, 1><<<dim3(D_ / 128, M / 128), blk, 0, stream>>>(
        (const void*)ao_bf, Wo, (void*)out, M, D_, QH_ * HD_);
}

// Round 2
// 2170.310 us; speedup vs baseline: 3.4174x; 3.4174x over previous
//
#include <hip/hip_runtime.h>
#include <cstdint>
#include <cstddef>

#define B_  2
#define S_  2048
#define D_  4096
#define QH_ 32
#define NH_ 8
#define HD_ 128

typedef __attribute__((ext_vector_type(8))) short bf16x8;
typedef __attribute__((ext_vector_type(4))) float f32x4;

__device__ __forceinline__ unsigned short f2bf(float f) {
    unsigned int u = __float_as_uint(f);
    return (unsigned short)((u + 0x7FFFu + ((u >> 16) & 1u)) >> 16);
}
__device__ __forceinline__ float bf2f(unsigned short h) { return __uint_as_float(((unsigned int)h) << 16); }
__device__ __forceinline__ float bflo(unsigned int u)   { return __uint_as_float(u << 16); }
__device__ __forceinline__ float bfhi(unsigned int u)   { return __uint_as_float(u & 0xffff0000u); }

// ---------------------------------------------------------------------------
// GEMM: C[M,N] = A[M,K] * B[K,N]   (unchanged from round 1 — passing)
// ---------------------------------------------------------------------------
template<int BMODE, int ABF, int CF32>
__global__ __launch_bounds__(256)
void gemm_kernel(const void* __restrict__ Ap, const float* __restrict__ Bp,
                 void* __restrict__ Cp, int M, int N, int K)
{
    constexpr int BM = 128, BN = 128, BK = 64, LDP = 72;
    __shared__ alignas(16) unsigned short As[BM][LDP];
    __shared__ alignas(16) unsigned short Bs[BN][LDP];

    const int t  = threadIdx.x;
    const int bn = blockIdx.x * BN;
    const int bm = blockIdx.y * BM;
    const int l  = t & 63, w = t >> 6;
    const int wr = w >> 1, wc = w & 1;
    const int lm = l & 15;
    const int lko = (l >> 4) * 8;

    f32x4 acc[4][4];
    const f32x4 zero = {0.f, 0.f, 0.f, 0.f};
    #pragma unroll
    for (int i = 0; i < 4; ++i)
        #pragma unroll
        for (int j = 0; j < 4; ++j) acc[i][j] = zero;

    const int nkt = K / BK;
    for (int kt = 0; kt < nkt; ++kt) {
        __syncthreads();
        if constexpr (ABF) {
            const unsigned short* A = (const unsigned short*)Ap;
            #pragma unroll
            for (int p = 0; p < 4; ++p) {
                int m  = p * 32 + (t >> 3);
                int k0 = (t & 7) * 8;
                uint4 v = *(const uint4*)(A + (size_t)(bm + m) * K + kt * BK + k0);
                *(uint4*)&As[m][k0] = v;
            }
        } else {
            const float* A = (const float*)Ap;
            #pragma unroll
            for (int p = 0; p < 8; ++p) {
                int m  = p * 16 + (t >> 4);
                int k0 = (t & 15) * 4;
                float4 v = *(const float4*)(A + (size_t)(bm + m) * K + kt * BK + k0);
                unsigned int lo = (unsigned int)f2bf(v.x) | ((unsigned int)f2bf(v.y) << 16);
                unsigned int hi = (unsigned int)f2bf(v.z) | ((unsigned int)f2bf(v.w) << 16);
                *(uint2*)&As[m][k0] = make_uint2(lo, hi);
            }
        }
        #pragma unroll
        for (int p = 0; p < 8; ++p) {
            int kk = p * 8 + (t >> 5);
            int n0 = (t & 31) * 4;
            size_t off;
            if constexpr (BMODE == 0)
                off = (size_t)(bn >> 7) * ((size_t)D_ * HD_) + (size_t)(kt * BK + kk) * HD_ + n0;
            else
                off = (size_t)(kt * BK + kk) * N + bn + n0;
            float4 v = *(const float4*)(Bp + off);
            Bs[n0 + 0][kk] = f2bf(v.x);
            Bs[n0 + 1][kk] = f2bf(v.y);
            Bs[n0 + 2][kk] = f2bf(v.z);
            Bs[n0 + 3][kk] = f2bf(v.w);
        }
        __syncthreads();
        #pragma unroll
        for (int kk = 0; kk < BK; kk += 32) {
            bf16x8 af[4], bfv[4];
            #pragma unroll
            for (int i = 0; i < 4; ++i) af[i]  = *(const bf16x8*)&As[wr * 64 + i * 16 + lm][kk + lko];
            #pragma unroll
            for (int j = 0; j < 4; ++j) bfv[j] = *(const bf16x8*)&Bs[wc * 64 + j * 16 + lm][kk + lko];
            #pragma unroll
            for (int i = 0; i < 4; ++i)
                #pragma unroll
                for (int j = 0; j < 4; ++j)
                    acc[i][j] = __builtin_amdgcn_mfma_f32_16x16x32_bf16(af[i], bfv[j], acc[i][j], 0, 0, 0);
        }
    }
    const int lr4 = (l >> 4) * 4;
    #pragma unroll
    for (int i = 0; i < 4; ++i) {
        #pragma unroll
        for (int j = 0; j < 4; ++j) {
            int row = bm + wr * 64 + i * 16 + lr4;
            int col = bn + wc * 64 + j * 16 + lm;
            #pragma unroll
            for (int jj = 0; jj < 4; ++jj) {
                if constexpr (CF32)
                    ((float*)Cp)[(size_t)(row + jj) * N + col] = acc[i][j][jj];
                else
                    ((unsigned short*)Cp)[(size_t)(row + jj) * N + col] = f2bf(acc[i][j][jj]);
            }
        }
    }
}

// ---------------------------------------------------------------------------
// RoPE in-place on bf16 [rows][128]  (unchanged)
// ---------------------------------------------------------------------------
template<int NHEADS>
__global__ __launch_bounds__(256)
void rope_kernel(unsigned short* __restrict__ data, const int* __restrict__ positions)
{
    const int gid = blockIdx.x * 256 + threadIdx.x;
    const int j   = gid & 63;
    const int row = gid >> 6;
    const int bs  = row / NHEADS;
    const float pos = (float)positions[bs];
    const float inv = expf(-0.14391156831f * (float)j);
    float s, c;
    sincosf(pos * inv, &s, &c);
    const size_t base = (size_t)row * HD_;
    const float x1 = bf2f(data[base + j]);
    const float x2 = bf2f(data[base + 64 + j]);
    data[base + j]      = f2bf(x1 * c - x2 * s);
    data[base + 64 + j] = f2bf(x2 * c + x1 * s);
}

// ---------------------------------------------------------------------------
// MFMA flash attention. Block = 256 thr (4 waves) = one (b, qh, 64 Q-rows).
// Wave w owns Q-rows w*16..w*16+15. 64-key chunks, online softmax.
// Fragment conventions identical to gemm_kernel (validated round 1):
//   A/B: elem j of lane l  <- buf[(idx16 = l&15)][k = (l>>4)*8 + j]
//   C/D: col = lane&15, row = (lane>>4)*4 + reg
// ---------------------------------------------------------------------------
__global__ __launch_bounds__(256)
void attn_kernel(const unsigned short* __restrict__ qr,
                 const unsigned short* __restrict__ kr,
                 const unsigned short* __restrict__ vr,
                 unsigned short* __restrict__ ao)
{
    constexpr int LDK = 136;  // 272 B row stride: 16B-aligned, bank offset 4/row
    constexpr int LDV = 72;   // 144 B row stride: same property
    __shared__ alignas(16) unsigned short k_s[64][LDK];   // [key][h]
    __shared__ alignas(16) unsigned short v_t[128][LDV];  // [h][key] (transposed)
    __shared__ alignas(16) unsigned short p_s[4][16][LDV];// per-wave P rows

    const int t   = threadIdx.x;
    const int blk = blockIdx.x;
    const int sb  = blk & 31;
    const int qh  = (blk >> 5) & 31;
    const int b   = blk >> 10;
    const int kh  = qh >> 2;
    const int l   = t & 63, w = t >> 6;
    const int lm  = l & 15;
    const int lg  = l >> 4;
    const int lko = lg * 8;

    // Q fragments straight from global (rows w*16+lm of this block's Q tile)
    bf16x8 qf[4];
    {
        const size_t qrow = ((size_t)(b * S_ + sb * 64 + w * 16 + lm) * QH_ + qh) * HD_;
        #pragma unroll
        for (int kk = 0; kk < 4; ++kk)
            qf[kk] = *(const bf16x8*)(qr + qrow + kk * 32 + lko);
    }

    f32x4 acc_o[8];
    #pragma unroll
    for (int i = 0; i < 8; ++i) acc_o[i] = (f32x4){0.f, 0.f, 0.f, 0.f};
    float mreg[4], lreg[4];
    #pragma unroll
    for (int r = 0; r < 4; ++r) { mreg[r] = -1e30f; lreg[r] = 0.f; }

    const float sm_scale = 0.08838834764831845f; // 1/sqrt(128)
    const size_t kv_head_base = ((size_t)b * S_) * NH_ + kh; // row units

    for (int c = 0; c <= sb; ++c) {
        __syncthreads(); // previous chunk fully consumed
        // ---- stage K [key][h] (coalesced) ----
        {
            const int key = t >> 2, seg = t & 3;
            const size_t g = ((size_t)(b * S_ + c * 64 + key) * NH_ + kh) * HD_ + seg * 32;
            const uint4* ksrc = (const uint4*)(kr + g);
            #pragma unroll
            for (int i = 0; i < 4; ++i)
                *(uint4*)&k_s[key][seg * 32 + i * 8] = ksrc[i];
        }
        // ---- stage V transposed -> v_t[h][key], xor-paired dword writes ----
        {
            const int key = l;           // lane == key so __shfl_xor(.,1) pairs keys
            const int odd = l & 1;
            const size_t vrow = ((size_t)(b * S_ + c * 64 + key) * NH_ + kh) * HD_;
            #pragma unroll
            for (int p = 0; p < 4; ++p) {
                const int h0 = (w + p * 4) * 8;
                uint4 v = *(const uint4*)(vr + vrow + h0);
                uint4 ov;
                ov.x = __shfl_xor(v.x, 1); ov.y = __shfl_xor(v.y, 1);
                ov.z = __shfl_xor(v.z, 1); ov.w = __shfl_xor(v.w, 1);
                // this lane writes rows h0+odd*4 .. +3 for the key pair (key&~1, key|1)
                unsigned int c0  = odd ? v.z  : v.x;
                unsigned int c1  = odd ? v.w  : v.y;
                unsigned int oc0 = odd ? ov.z : ov.x;
                unsigned int oc1 = odd ? ov.w : ov.y;
                const int colw = (l >> 1); // dword column (key pair)
                #pragma unroll
                for (int j = 0; j < 4; ++j) {
                    unsigned int mine = (j & 1) ? ((j & 2) ? (c1 >> 16) : (c0 >> 16))
                                                : ((j & 2) ? (c1 & 0xffffu) : (c0 & 0xffffu));
                    unsigned int oth  = (j & 1) ? ((j & 2) ? (oc1 >> 16) : (oc0 >> 16))
                                                : ((j & 2) ? (oc1 & 0xffffu) : (oc0 & 0xffffu));
                    unsigned int packed = odd ? (oth | (mine << 16)) : (mine | (oth << 16));
                    *(unsigned int*)&v_t[h0 + odd * 4 + j][colw * 2] = packed;
                }
            }
        }
        __syncthreads();

        // ---- QK^T: S-tile 16 rows x 64 keys per wave ----
        f32x4 acc_s[4];
        #pragma unroll
        for (int t4 = 0; t4 < 4; ++t4) acc_s[t4] = (f32x4){0.f, 0.f, 0.f, 0.f};
        #pragma unroll
        for (int kk = 0; kk < 4; ++kk) {
            const bf16x8 a = qf[kk];
            #pragma unroll
            for (int t4 = 0; t4 < 4; ++t4) {
                const bf16x8 bv = *(const bf16x8*)&k_s[t4 * 16 + lm][kk * 32 + lko];
                acc_s[t4] = __builtin_amdgcn_mfma_f32_16x16x32_bf16(a, bv, acc_s[t4], 0, 0, 0);
            }
        }

        // ---- online softmax (lane owns rows lg*4+r, col key t4*16+lm) ----
        const bool diag = (c == sb);
        float sc[4][4];
        #pragma unroll
        for (int t4 = 0; t4 < 4; ++t4)
            #pragma unroll
            for (int r = 0; r < 4; ++r) {
                float s = acc_s[t4][r] * sm_scale;
                if (diag && (t4 * 16 + lm > w * 16 + lg * 4 + r)) s = -1e30f;
                sc[t4][r] = s;
            }
        #pragma unroll
        for (int r = 0; r < 4; ++r) {
            float mc = fmaxf(fmaxf(sc[0][r], sc[1][r]), fmaxf(sc[2][r], sc[3][r]));
            #pragma unroll
            for (int off = 1; off < 16; off <<= 1) mc = fmaxf(mc, __shfl_xor(mc, off, 64));
            const float mnew = fmaxf(mreg[r], mc);
            const float sf = __expf(mreg[r] - mnew);
            mreg[r] = mnew;
            float pv[4];
            #pragma unroll
            for (int t4 = 0; t4 < 4; ++t4) pv[t4] = __expf(sc[t4][r] - mnew);
            float ps = pv[0] + pv[1] + pv[2] + pv[3];
            #pragma unroll
            for (int off = 1; off < 16; off <<= 1) ps += __shfl_xor(ps, off, 64);
            lreg[r] = lreg[r] * sf + ps;
            #pragma unroll
            for (int ht = 0; ht < 8; ++ht) acc_o[ht][r] *= sf;
            // P -> bf16 LDS (wave-private, no barrier), paired dword writes
            #pragma unroll
            for (int t4 = 0; t4 < 4; ++t4) {
                const float po = __shfl_xor(pv[t4], 1);
                if (!(l & 1)) {
                    unsigned int packed = (unsigned int)f2bf(pv[t4])
                                        | ((unsigned int)f2bf(po) << 16);
                    *(unsigned int*)&p_s[w][lg * 4 + r][t4 * 16 + lm] = packed;
                }
            }
        }

        // ---- PV: out-tile 16 rows x 128 h per wave ----
        #pragma unroll
        for (int kk = 0; kk < 2; ++kk) {
            const bf16x8 pa = *(const bf16x8*)&p_s[w][lm][kk * 32 + lko];
            #pragma unroll
            for (int ht = 0; ht < 8; ++ht) {
                const bf16x8 bv = *(const bf16x8*)&v_t[ht * 16 + lm][kk * 32 + lko];
                acc_o[ht] = __builtin_amdgcn_mfma_f32_16x16x32_bf16(pa, bv, acc_o[ht], 0, 0, 0);
            }
        }
    }

    // ---- epilogue: normalize + write bf16 [row][qh*128 + h] ----
    #pragma unroll
    for (int r = 0; r < 4; ++r) {
        const float invl = 1.f / lreg[r];
        const size_t row = (size_t)(b * S_ + sb * 64 + w * 16 + lg * 4 + r);
        #pragma unroll
        for (int ht = 0; ht < 8; ++ht)
            ao[(row * QH_ + qh) * HD_ + ht * 16 + lm] = f2bf(acc_o[ht][r] * invl);
    }
}

// ---------------------------------------------------------------------------
extern "C" void kernel_launch(void* const* d_in, const int* in_sizes, int n_in,
                              void* d_out, int out_size, void* d_ws, size_t ws_size,
                              hipStream_t stream)
{
    const float* x  = (const float*)d_in[0];
    const int*  pos = (const int*)d_in[1];
    const float* Wq = (const float*)d_in[2];
    const float* Wk = (const float*)d_in[3];
    const float* Wv = (const float*)d_in[4];
    const float* Wo = (const float*)d_in[5];
    float* out = (float*)d_out;

    char* wsb = (char*)d_ws;
    unsigned short* q_bf  = (unsigned short*)(wsb);              // 32 MiB
    unsigned short* k_bf  = (unsigned short*)(wsb + 33554432);   //  8 MiB
    unsigned short* v_bf  = (unsigned short*)(wsb + 41943040);   //  8 MiB
    unsigned short* ao_bf = (unsigned short*)(wsb + 50331648);   // 32 MiB

    const dim3 blk(256);
    const int M = B_ * S_;             // 4096
    gemm_kernel<0, 0, 0><<<dim3((QH_ * HD_) / 128, M / 128), blk, 0, stream>>>(
        (const void*)x, Wq, (void*)q_bf, M, QH_ * HD_, D_);
    gemm_kernel<0, 0, 0><<<dim3((NH_ * HD_) / 128, M / 128), blk, 0, stream>>>(
        (const void*)x, Wk, (void*)k_bf, M, NH_ * HD_, D_);
    gemm_kernel<0, 0, 0><<<dim3((NH_ * HD_) / 128, M / 128), blk, 0, stream>>>(
        (const void*)x, Wv, (void*)v_bf, M, NH_ * HD_, D_);
    rope_kernel<QH_><<<(B_ * S_ * QH_ * 64) / 256, blk, 0, stream>>>(q_bf, pos);
    rope_kernel<NH_><<<(B_ * S_ * NH_ * 64) / 256, blk, 0, stream>>>(k_bf, pos);
    attn_kernel<<<B_ * QH_ * (S_ / 64), blk, 0, stream>>>(q_bf, k_bf, v_bf, ao_bf);
    gemm_kernel<1, 1, 1><<<dim3(D_ / 128, M / 128), blk, 0, stream>>>(
        (const void*)ao_bf, Wo, (void*)out, M, D_, QH_ * HD_);
}

// Round 3
// 1001.050 us; speedup vs baseline: 7.4090x; 2.1680x over previous
//
#include <hip/hip_runtime.h>
#include <cstdint>
#include <cstddef>

#define B_  2
#define S_  2048
#define D_  4096
#define QH_ 32
#define NH_ 8
#define HD_ 128
#define MROWS (B_ * S_)                      // 4096
#define NQKV  (QH_ * HD_ + 2 * NH_ * HD_)    // 6144
#define KOFF  (QH_ * HD_)                    // 4096
#define VOFF  (QH_ * HD_ + NH_ * HD_)        // 5120

typedef __attribute__((ext_vector_type(8))) short bf16x8;
typedef __attribute__((ext_vector_type(4))) float f32x4;

__device__ __forceinline__ unsigned short f2bf(float f) {
    unsigned int u = __float_as_uint(f);
    return (unsigned short)((u + 0x7FFFu + ((u >> 16) & 1u)) >> 16);
}
__device__ __forceinline__ float bf2f(unsigned short h) { return __uint_as_float(((unsigned int)h) << 16); }

// async global->LDS, 16B per lane; LDS dest is wave-uniform base + lane*16
__device__ __forceinline__ void gl2lds16(const void* g, void* l) {
    __builtin_amdgcn_global_load_lds(
        (const __attribute__((address_space(1))) void*)g,
        (__attribute__((address_space(3))) void*)l, 16, 0, 0);
}

// ---------------------------------------------------------------------------
// fp32 -> bf16 straight convert (x). 8 elems/thread, exact-grid.
// ---------------------------------------------------------------------------
__global__ __launch_bounds__(256)
void convert_bf16_kernel(const float* __restrict__ in, unsigned short* __restrict__ out)
{
    const size_t i = ((size_t)blockIdx.x * 256 + threadIdx.x) * 8;
    float4 a = *(const float4*)(in + i);
    float4 b = *(const float4*)(in + i + 4);
    uint4 o;
    o.x = (unsigned int)f2bf(a.x) | ((unsigned int)f2bf(a.y) << 16);
    o.y = (unsigned int)f2bf(a.z) | ((unsigned int)f2bf(a.w) << 16);
    o.z = (unsigned int)f2bf(b.x) | ((unsigned int)f2bf(b.y) << 16);
    o.w = (unsigned int)f2bf(b.z) | ((unsigned int)f2bf(b.w) << 16);
    *(uint4*)(out + i) = o;
}

// ---------------------------------------------------------------------------
// Tile transpose-convert: in fp32 [R][C] (per blockIdx.z slab) -> out bf16 [C][R]
// 64x64 tiles via LDS.
// ---------------------------------------------------------------------------
__global__ __launch_bounds__(256)
void transpose_conv_kernel(const float* __restrict__ in, unsigned short* __restrict__ out,
                           int R, int C)
{
    __shared__ unsigned short tile[64][72];
    const int t  = threadIdx.x;
    const int c0 = blockIdx.x * 64;
    const int r0 = blockIdx.y * 64;
    in  += (size_t)blockIdx.z * R * C;
    out += (size_t)blockIdx.z * R * C;
    {
        const int rr = t >> 4;
        const int cc = (t & 15) * 4;
        #pragma unroll
        for (int p = 0; p < 4; ++p) {
            float4 v = *(const float4*)(in + (size_t)(r0 + p * 16 + rr) * C + c0 + cc);
            unsigned int lo = (unsigned int)f2bf(v.x) | ((unsigned int)f2bf(v.y) << 16);
            unsigned int hi = (unsigned int)f2bf(v.z) | ((unsigned int)f2bf(v.w) << 16);
            *(uint2*)&tile[p * 16 + rr][cc] = make_uint2(lo, hi);
        }
    }
    __syncthreads();
    {
        const int j  = t >> 3;
        const int i8 = (t & 7) * 8;
        #pragma unroll
        for (int p = 0; p < 2; ++p) {
            unsigned short tmp[8];
            #pragma unroll
            for (int e = 0; e < 8; ++e) tmp[e] = tile[i8 + e][p * 32 + j];
            *(uint4*)(out + (size_t)(c0 + p * 32 + j) * R + r0 + i8) = *(uint4*)tmp;
        }
    }
}

// ---------------------------------------------------------------------------
// m97-structure GEMM: C[M,N] = A[M,K] * Bt[N,K]^T, all bf16 operands.
// 128x128 tile, BK=64, 4 waves, global_load_lds dwordx4 staging, linear LDS.
// CF32: C fp32 else bf16. Nst = C row stride.
// ---------------------------------------------------------------------------
template<int CF32>
__global__ __launch_bounds__(256)
void gemm_bt_kernel(const unsigned short* __restrict__ A,
                    const unsigned short* __restrict__ Bt,
                    void* __restrict__ Cp, int Nst, int K)
{
    __shared__ alignas(16) unsigned short As[128][64];
    __shared__ alignas(16) unsigned short Bs[128][64];
    const int t  = threadIdx.x, l = t & 63, w = t >> 6;
    const int bn = blockIdx.x * 128, bm = blockIdx.y * 128;
    const int wr = w >> 1, wc = w & 1, lm = l & 15, lko = (l >> 4) * 8;

    f32x4 acc[4][4];
    #pragma unroll
    for (int i = 0; i < 4; ++i)
        #pragma unroll
        for (int j = 0; j < 4; ++j) acc[i][j] = (f32x4){0.f, 0.f, 0.f, 0.f};

    // staging: wave w, chunk c covers LDS rows c*32 + w*8 .. +7
    const int srow = w * 8 + (l >> 3);
    const int scol = (l & 7) * 8;
    const unsigned short* Ab = A  + (size_t)(bm + srow) * K + scol;
    const unsigned short* Bb = Bt + (size_t)(bn + srow) * K + scol;
    char* AsB = (char*)&As[0][0] + w * 1024;
    char* BsB = (char*)&Bs[0][0] + w * 1024;

    for (int kt = 0; kt < K; kt += 64) {
        __syncthreads();
        #pragma unroll
        for (int c = 0; c < 4; ++c) {
            gl2lds16(Ab + (size_t)(c * 32) * K + kt, AsB + c * 4096);
            gl2lds16(Bb + (size_t)(c * 32) * K + kt, BsB + c * 4096);
        }
        __syncthreads();
        #pragma unroll
        for (int kk = 0; kk < 64; kk += 32) {
            bf16x8 af[4], bv[4];
            #pragma unroll
            for (int i = 0; i < 4; ++i) af[i] = *(const bf16x8*)&As[wr * 64 + i * 16 + lm][kk + lko];
            #pragma unroll
            for (int j = 0; j < 4; ++j) bv[j] = *(const bf16x8*)&Bs[wc * 64 + j * 16 + lm][kk + lko];
            #pragma unroll
            for (int i = 0; i < 4; ++i)
                #pragma unroll
                for (int j = 0; j < 4; ++j)
                    acc[i][j] = __builtin_amdgcn_mfma_f32_16x16x32_bf16(af[i], bv[j], acc[i][j], 0, 0, 0);
        }
    }
    // C/D: col = lane&15, row = (lane>>4)*4 + reg (HW-verified convention)
    const int lr4 = (l >> 4) * 4;
    #pragma unroll
    for (int i = 0; i < 4; ++i) {
        #pragma unroll
        for (int j = 0; j < 4; ++j) {
            int row = bm + wr * 64 + i * 16 + lr4;
            int col = bn + wc * 64 + j * 16 + lm;
            #pragma unroll
            for (int jj = 0; jj < 4; ++jj) {
                if constexpr (CF32)
                    ((float*)Cp)[(size_t)(row + jj) * Nst + col] = acc[i][j][jj];
                else
                    ((unsigned short*)Cp)[(size_t)(row + jj) * Nst + col] = f2bf(acc[i][j][jj]);
            }
        }
    }
}

// ---------------------------------------------------------------------------
// RoPE in-place on bf16 slab of the fused qkv buffer (row stride NQKV).
// data = qkv + column base; head-major cols head*128 + j / +64+j.
// ---------------------------------------------------------------------------
template<int LOG2H>
__global__ __launch_bounds__(256)
void rope_kernel(unsigned short* __restrict__ data, const int* __restrict__ positions)
{
    const int gid  = blockIdx.x * 256 + threadIdx.x;
    const int j    = gid & 63;
    const int hr   = gid >> 6;
    const int head = hr & ((1 << LOG2H) - 1);
    const int bs   = hr >> LOG2H;
    const float pos = (float)positions[bs];
    const float inv = expf(-0.14391156831f * (float)j);  // 10000^(-j/64)
    float s, c;
    sincosf(pos * inv, &s, &c);
    const size_t base = (size_t)bs * NQKV + head * HD_;
    const float x1 = bf2f(data[base + j]);
    const float x2 = bf2f(data[base + 64 + j]);
    data[base + j]      = f2bf(x1 * c - x2 * s);
    data[base + 64 + j] = f2bf(x2 * c + x1 * s);
}

// ---------------------------------------------------------------------------
// MFMA flash attention (unchanged math from round 2; reads fused qkv buffer).
// ---------------------------------------------------------------------------
__global__ __launch_bounds__(256)
void attn_kernel(const unsigned short* __restrict__ qkv,
                 unsigned short* __restrict__ ao)
{
    constexpr int LDK = 136;
    constexpr int LDV = 72;
    __shared__ alignas(16) unsigned short k_s[64][LDK];
    __shared__ alignas(16) unsigned short v_t[128][LDV];
    __shared__ alignas(16) unsigned short p_s[4][16][LDV];

    const int t   = threadIdx.x;
    const int blk = blockIdx.x;
    const int sb  = blk & 31;
    const int qh  = (blk >> 5) & 31;
    const int b   = blk >> 10;
    const int kh  = qh >> 2;
    const int l   = t & 63, w = t >> 6;
    const int lm  = l & 15;
    const int lg  = l >> 4;
    const int lko = lg * 8;

    bf16x8 qf[4];
    {
        const size_t qrow = (size_t)(b * S_ + sb * 64 + w * 16 + lm) * NQKV + qh * HD_;
        #pragma unroll
        for (int kk = 0; kk < 4; ++kk)
            qf[kk] = *(const bf16x8*)(qkv + qrow + kk * 32 + lko);
    }

    f32x4 acc_o[8];
    #pragma unroll
    for (int i = 0; i < 8; ++i) acc_o[i] = (f32x4){0.f, 0.f, 0.f, 0.f};
    float mreg[4], lreg[4];
    #pragma unroll
    for (int r = 0; r < 4; ++r) { mreg[r] = -1e30f; lreg[r] = 0.f; }

    const float sm_scale = 0.08838834764831845f;

    for (int c = 0; c <= sb; ++c) {
        __syncthreads();
        {
            const int key = t >> 2, seg = t & 3;
            const size_t g = (size_t)(b * S_ + c * 64 + key) * NQKV + KOFF + kh * HD_ + seg * 32;
            const uint4* ksrc = (const uint4*)(qkv + g);
            #pragma unroll
            for (int i = 0; i < 4; ++i)
                *(uint4*)&k_s[key][seg * 32 + i * 8] = ksrc[i];
        }
        {
            const int key = l;
            const int odd = l & 1;
            const size_t vrow = (size_t)(b * S_ + c * 64 + key) * NQKV + VOFF + kh * HD_;
            #pragma unroll
            for (int p = 0; p < 4; ++p) {
                const int h0 = (w + p * 4) * 8;
                uint4 v = *(const uint4*)(qkv + vrow + h0);
                uint4 ov;
                ov.x = __shfl_xor(v.x, 1); ov.y = __shfl_xor(v.y, 1);
                ov.z = __shfl_xor(v.z, 1); ov.w = __shfl_xor(v.w, 1);
                unsigned int c0  = odd ? v.z  : v.x;
                unsigned int c1  = odd ? v.w  : v.y;
                unsigned int oc0 = odd ? ov.z : ov.x;
                unsigned int oc1 = odd ? ov.w : ov.y;
                const int colw = (l >> 1);
                #pragma unroll
                for (int j = 0; j < 4; ++j) {
                    unsigned int mine = (j & 1) ? ((j & 2) ? (c1 >> 16) : (c0 >> 16))
                                                : ((j & 2) ? (c1 & 0xffffu) : (c0 & 0xffffu));
                    unsigned int oth  = (j & 1) ? ((j & 2) ? (oc1 >> 16) : (oc0 >> 16))
                                                : ((j & 2) ? (oc1 & 0xffffu) : (oc0 & 0xffffu));
                    unsigned int packed = odd ? (oth | (mine << 16)) : (mine | (oth << 16));
                    *(unsigned int*)&v_t[h0 + odd * 4 + j][colw * 2] = packed;
                }
            }
        }
        __syncthreads();

        f32x4 acc_s[4];
        #pragma unroll
        for (int t4 = 0; t4 < 4; ++t4) acc_s[t4] = (f32x4){0.f, 0.f, 0.f, 0.f};
        #pragma unroll
        for (int kk = 0; kk < 4; ++kk) {
            const bf16x8 a = qf[kk];
            #pragma unroll
            for (int t4 = 0; t4 < 4; ++t4) {
                const bf16x8 bv = *(const bf16x8*)&k_s[t4 * 16 + lm][kk * 32 + lko];
                acc_s[t4] = __builtin_amdgcn_mfma_f32_16x16x32_bf16(a, bv, acc_s[t4], 0, 0, 0);
            }
        }

        const bool diag = (c == sb);
        float sc[4][4];
        #pragma unroll
        for (int t4 = 0; t4 < 4; ++t4)
            #pragma unroll
            for (int r = 0; r < 4; ++r) {
                float s = acc_s[t4][r] * sm_scale;
                if (diag && (t4 * 16 + lm > w * 16 + lg * 4 + r)) s = -1e30f;
                sc[t4][r] = s;
            }
        #pragma unroll
        for (int r = 0; r < 4; ++r) {
            float mc = fmaxf(fmaxf(sc[0][r], sc[1][r]), fmaxf(sc[2][r], sc[3][r]));
            #pragma unroll
            for (int off = 1; off < 16; off <<= 1) mc = fmaxf(mc, __shfl_xor(mc, off, 64));
            const float mnew = fmaxf(mreg[r], mc);
            const float sf = __expf(mreg[r] - mnew);
            mreg[r] = mnew;
            float pv[4];
            #pragma unroll
            for (int t4 = 0; t4 < 4; ++t4) pv[t4] = __expf(sc[t4][r] - mnew);
            float ps = pv[0] + pv[1] + pv[2] + pv[3];
            #pragma unroll
            for (int off = 1; off < 16; off <<= 1) ps += __shfl_xor(ps, off, 64);
            lreg[r] = lreg[r] * sf + ps;
            #pragma unroll
            for (int ht = 0; ht < 8; ++ht) acc_o[ht][r] *= sf;
            #pragma unroll
            for (int t4 = 0; t4 < 4; ++t4) {
                const float po = __shfl_xor(pv[t4], 1);
                if (!(l & 1)) {
                    unsigned int packed = (unsigned int)f2bf(pv[t4])
                                        | ((unsigned int)f2bf(po) << 16);
                    *(unsigned int*)&p_s[w][lg * 4 + r][t4 * 16 + lm] = packed;
                }
            }
        }

        #pragma unroll
        for (int kk = 0; kk < 2; ++kk) {
            const bf16x8 pa = *(const bf16x8*)&p_s[w][lm][kk * 32 + lko];
            #pragma unroll
            for (int ht = 0; ht < 8; ++ht) {
                const bf16x8 bv = *(const bf16x8*)&v_t[ht * 16 + lm][kk * 32 + lko];
                acc_o[ht] = __builtin_amdgcn_mfma_f32_16x16x32_bf16(pa, bv, acc_o[ht], 0, 0, 0);
            }
        }
    }

    #pragma unroll
    for (int r = 0; r < 4; ++r) {
        const float invl = 1.f / lreg[r];
        const size_t row = (size_t)(b * S_ + sb * 64 + w * 16 + lg * 4 + r);
        #pragma unroll
        for (int ht = 0; ht < 8; ++ht)
            ao[(row * QH_ + qh) * HD_ + ht * 16 + lm] = f2bf(acc_o[ht][r] * invl);
    }
}

// ---------------------------------------------------------------------------
extern "C" void kernel_launch(void* const* d_in, const int* in_sizes, int n_in,
                              void* d_out, int out_size, void* d_ws, size_t ws_size,
                              hipStream_t stream)
{
    const float* x  = (const float*)d_in[0];
    const int*  pos = (const int*)d_in[1];
    const float* Wq = (const float*)d_in[2];
    const float* Wk = (const float*)d_in[3];
    const float* Wv = (const float*)d_in[4];
    const float* Wo = (const float*)d_in[5];
    float* out = (float*)d_out;

    char* wsb = (char*)d_ws;
    unsigned short* qkv = (unsigned short*)(wsb);              // 48 MiB [4096][6144]
    unsigned short* wt  = (unsigned short*)(wsb + 50331648);   // 48 MiB Wt_qkv -> Wt_o
    unsigned short* r0  = (unsigned short*)(wsb + 100663296);  // 32 MiB x_bf -> ao

    const dim3 blk(256);
    // prep: x -> bf16; Wq/Wk/Wv -> Wt[6144][4096] (B^T layout)
    convert_bf16_kernel<<<8192, blk, 0, stream>>>(x, r0);
    transpose_conv_kernel<<<dim3(2, 64, 32), blk, 0, stream>>>(Wq, wt, D_, HD_);
    transpose_conv_kernel<<<dim3(2, 64, 8),  blk, 0, stream>>>(Wk, wt + (size_t)KOFF * D_, D_, HD_);
    transpose_conv_kernel<<<dim3(2, 64, 8),  blk, 0, stream>>>(Wv, wt + (size_t)VOFF * D_, D_, HD_);
    // fused QKV projection: [4096][6144]
    gemm_bt_kernel<0><<<dim3(NQKV / 128, MROWS / 128), blk, 0, stream>>>(r0, wt, qkv, NQKV, D_);
    // Wo -> Wt_o (reuses wt region; ordered after QKV gemm on stream)
    transpose_conv_kernel<<<dim3(64, 64, 1), blk, 0, stream>>>(Wo, wt, D_, D_);
    // RoPE on Q and K slabs of qkv
    rope_kernel<5><<<(MROWS * QH_ * 64) / 256, blk, 0, stream>>>(qkv, pos);
    rope_kernel<3><<<(MROWS * NH_ * 64) / 256, blk, 0, stream>>>(qkv + KOFF, pos);
    // attention -> ao (reuses r0)
    attn_kernel<<<B_ * QH_ * (S_ / 64), blk, 0, stream>>>(qkv, r0);
    // output projection -> fp32 out
    gemm_bt_kernel<1><<<dim3(D_ / 128, MROWS / 128), blk, 0, stream>>>(r0, wt, out, D_, QH_ * HD_);
}

// Round 4
// 794.459 us; speedup vs baseline: 9.3357x; 1.2600x over previous
//
#include <hip/hip_runtime.h>
#include <cstdint>
#include <cstddef>

#define B_  2
#define S_  2048
#define D_  4096
#define QH_ 32
#define NH_ 8
#define HD_ 128
#define MROWS (B_ * S_)                      // 4096
#define NQKV  (QH_ * HD_ + 2 * NH_ * HD_)    // 6144
#define KOFF  (QH_ * HD_)                    // 4096
#define VOFF  (QH_ * HD_ + NH_ * HD_)        // 5120

typedef __attribute__((ext_vector_type(8))) short bf16x8;
typedef __attribute__((ext_vector_type(4))) float f32x4;

__device__ __forceinline__ unsigned short f2bf(float f) {
    unsigned int u = __float_as_uint(f);
    return (unsigned short)((u + 0x7FFFu + ((u >> 16) & 1u)) >> 16);
}
__device__ __forceinline__ float bf2f(unsigned short h) { return __uint_as_float(((unsigned int)h) << 16); }

__device__ __forceinline__ void gl2lds16(const void* g, void* l) {
    __builtin_amdgcn_global_load_lds(
        (const __attribute__((address_space(1))) void*)g,
        (__attribute__((address_space(3))) void*)l, 16, 0, 0);
}

// ---------------------------------------------------------------------------
// fp32 -> bf16 straight convert (x). 8 elems/thread.
// ---------------------------------------------------------------------------
__global__ __launch_bounds__(256)
void convert_bf16_kernel(const float* __restrict__ in, unsigned short* __restrict__ out)
{
    const size_t i = ((size_t)blockIdx.x * 256 + threadIdx.x) * 8;
    float4 a = *(const float4*)(in + i);
    float4 b = *(const float4*)(in + i + 4);
    uint4 o;
    o.x = (unsigned int)f2bf(a.x) | ((unsigned int)f2bf(a.y) << 16);
    o.y = (unsigned int)f2bf(a.z) | ((unsigned int)f2bf(a.w) << 16);
    o.z = (unsigned int)f2bf(b.x) | ((unsigned int)f2bf(b.y) << 16);
    o.w = (unsigned int)f2bf(b.z) | ((unsigned int)f2bf(b.w) << 16);
    *(uint4*)(out + i) = o;
}

// ---------------------------------------------------------------------------
// Tile transpose-convert: in fp32 [R][C] (slab z) -> out bf16 [C][R]
// ---------------------------------------------------------------------------
__global__ __launch_bounds__(256)
void transpose_conv_kernel(const float* __restrict__ in, unsigned short* __restrict__ out,
                           int R, int C)
{
    __shared__ unsigned short tile[64][72];
    const int t  = threadIdx.x;
    const int c0 = blockIdx.x * 64;
    const int r0 = blockIdx.y * 64;
    in  += (size_t)blockIdx.z * R * C;
    out += (size_t)blockIdx.z * R * C;
    {
        const int rr = t >> 4;
        const int cc = (t & 15) * 4;
        #pragma unroll
        for (int p = 0; p < 4; ++p) {
            float4 v = *(const float4*)(in + (size_t)(r0 + p * 16 + rr) * C + c0 + cc);
            unsigned int lo = (unsigned int)f2bf(v.x) | ((unsigned int)f2bf(v.y) << 16);
            unsigned int hi = (unsigned int)f2bf(v.z) | ((unsigned int)f2bf(v.w) << 16);
            *(uint2*)&tile[p * 16 + rr][cc] = make_uint2(lo, hi);
        }
    }
    __syncthreads();
    {
        const int j  = t >> 3;
        const int i8 = (t & 7) * 8;
        #pragma unroll
        for (int p = 0; p < 2; ++p) {
            unsigned short tmp[8];
            #pragma unroll
            for (int e = 0; e < 8; ++e) tmp[e] = tile[i8 + e][p * 32 + j];
            *(uint4*)(out + (size_t)(c0 + p * 32 + j) * R + r0 + i8) = *(uint4*)tmp;
        }
    }
}

// ---------------------------------------------------------------------------
// bf16 transpose of the V slab of qkv: -> vt[(b*8+kh)*128 + h][2048 s]
// ---------------------------------------------------------------------------
__global__ __launch_bounds__(256)
void transpose_v_kernel(const unsigned short* __restrict__ qkv, unsigned short* __restrict__ vt)
{
    __shared__ unsigned short tile[64][76];
    const int t  = threadIdx.x;
    const int z  = blockIdx.z;            // b*8+kh
    const int b  = z >> 3, kh = z & 7;
    const int h0 = blockIdx.x * 64;
    const int s0 = blockIdx.y * 64;
    const unsigned short* in = qkv + (size_t)(b * S_) * NQKV + VOFF + kh * HD_;
    unsigned short* outb = vt + (size_t)z * HD_ * S_;
    {
        const int rr = t >> 4;            // s-local
        const int cc = (t & 15) * 4;      // h-local
        #pragma unroll
        for (int p = 0; p < 4; ++p) {
            uint2 v = *(const uint2*)(in + (size_t)(s0 + p * 16 + rr) * NQKV + h0 + cc);
            *(uint2*)&tile[p * 16 + rr][cc] = v;
        }
    }
    __syncthreads();
    {
        const int j  = t >> 3;            // h-local 0..31
        const int i8 = (t & 7) * 8;       // s-local
        #pragma unroll
        for (int p = 0; p < 2; ++p) {
            unsigned short tmp[8];
            #pragma unroll
            for (int e = 0; e < 8; ++e) tmp[e] = tile[i8 + e][p * 32 + j];
            *(uint4*)(outb + (size_t)(h0 + p * 32 + j) * S_ + s0 + i8) = *(uint4*)tmp;
        }
    }
}

// ---------------------------------------------------------------------------
// m97-structure GEMM: C[M,N] = A[M,K] * Bt[N,K]^T, bf16 operands, XCD swizzle.
// ---------------------------------------------------------------------------
template<int CF32>
__global__ __launch_bounds__(256)
void gemm_bt_kernel(const unsigned short* __restrict__ A,
                    const unsigned short* __restrict__ Bt,
                    void* __restrict__ Cp, int Nst, int K)
{
    __shared__ alignas(16) unsigned short As[128][64];
    __shared__ alignas(16) unsigned short Bs[128][64];
    const int t  = threadIdx.x, l = t & 63, w = t >> 6;
    // bijective XCD swizzle (nwg % 8 == 0 for both uses)
    const int gx  = gridDim.x;
    const int nwg = gx * gridDim.y;
    int lin = blockIdx.y * gx + blockIdx.x;
    lin = (lin & 7) * (nwg >> 3) + (lin >> 3);
    const int bn = (lin % gx) * 128, bm = (lin / gx) * 128;
    const int wr = w >> 1, wc = w & 1, lm = l & 15, lko = (l >> 4) * 8;

    f32x4 acc[4][4];
    #pragma unroll
    for (int i = 0; i < 4; ++i)
        #pragma unroll
        for (int j = 0; j < 4; ++j) acc[i][j] = (f32x4){0.f, 0.f, 0.f, 0.f};

    const int srow = w * 8 + (l >> 3);
    const int scol = (l & 7) * 8;
    const unsigned short* Ab = A  + (size_t)(bm + srow) * K + scol;
    const unsigned short* Bb = Bt + (size_t)(bn + srow) * K + scol;
    char* AsB = (char*)&As[0][0] + w * 1024;
    char* BsB = (char*)&Bs[0][0] + w * 1024;

    for (int kt = 0; kt < K; kt += 64) {
        __syncthreads();
        #pragma unroll
        for (int c = 0; c < 4; ++c) {
            gl2lds16(Ab + (size_t)(c * 32) * K + kt, AsB + c * 4096);
            gl2lds16(Bb + (size_t)(c * 32) * K + kt, BsB + c * 4096);
        }
        __syncthreads();
        #pragma unroll
        for (int kk = 0; kk < 64; kk += 32) {
            bf16x8 af[4], bv[4];
            #pragma unroll
            for (int i = 0; i < 4; ++i) af[i] = *(const bf16x8*)&As[wr * 64 + i * 16 + lm][kk + lko];
            #pragma unroll
            for (int j = 0; j < 4; ++j) bv[j] = *(const bf16x8*)&Bs[wc * 64 + j * 16 + lm][kk + lko];
            __builtin_amdgcn_s_setprio(1);
            #pragma unroll
            for (int i = 0; i < 4; ++i)
                #pragma unroll
                for (int j = 0; j < 4; ++j)
                    acc[i][j] = __builtin_amdgcn_mfma_f32_16x16x32_bf16(af[i], bv[j], acc[i][j], 0, 0, 0);
            __builtin_amdgcn_s_setprio(0);
        }
    }
    const int lr4 = (l >> 4) * 4;
    #pragma unroll
    for (int i = 0; i < 4; ++i) {
        #pragma unroll
        for (int j = 0; j < 4; ++j) {
            int row = bm + wr * 64 + i * 16 + lr4;
            int col = bn + wc * 64 + j * 16 + lm;
            #pragma unroll
            for (int jj = 0; jj < 4; ++jj) {
                if constexpr (CF32)
                    ((float*)Cp)[(size_t)(row + jj) * Nst + col] = acc[i][j][jj];
                else
                    ((unsigned short*)Cp)[(size_t)(row + jj) * Nst + col] = f2bf(acc[i][j][jj]);
            }
        }
    }
}

// ---------------------------------------------------------------------------
// RoPE in-place on a slab of qkv (row stride NQKV).
// ---------------------------------------------------------------------------
template<int LOG2H>
__global__ __launch_bounds__(256)
void rope_kernel(unsigned short* __restrict__ data, const int* __restrict__ positions)
{
    const int gid  = blockIdx.x * 256 + threadIdx.x;
    const int j    = gid & 63;
    const int hr   = gid >> 6;
    const int head = hr & ((1 << LOG2H) - 1);
    const int bs   = hr >> LOG2H;
    const float pos = (float)positions[bs];
    const float inv = expf(-0.14391156831f * (float)j);
    float s, c;
    sincosf(pos * inv, &s, &c);
    const size_t base = (size_t)bs * NQKV + head * HD_;
    const float x1 = bf2f(data[base + j]);
    const float x2 = bf2f(data[base + 64 + j]);
    data[base + j]      = f2bf(x1 * c - x2 * s);
    data[base + 64 + j] = f2bf(x2 * c + x1 * s);
}

// ---------------------------------------------------------------------------
// MFMA flash attention. V pre-transposed in global (vt). Heavy blocks first.
// ---------------------------------------------------------------------------
__global__ __launch_bounds__(256)
void attn_kernel(const unsigned short* __restrict__ qkv,
                 const unsigned short* __restrict__ vt,
                 unsigned short* __restrict__ ao)
{
    constexpr int LDK = 136;
    constexpr int LDV = 72;
    __shared__ alignas(16) unsigned short k_s[64][LDK];
    __shared__ alignas(16) unsigned short v_t[128][LDV];
    __shared__ alignas(16) unsigned short p_s[4][16][LDV];

    const int t   = threadIdx.x;
    const int blk = blockIdx.x;
    const int sb  = 31 - (blk >> 6);     // heavy (sb=31) blocks launch first
    const int pr  = blk & 63;
    const int qh  = pr >> 1;
    const int b   = pr & 1;
    const int kh  = qh >> 2;
    const int l   = t & 63, w = t >> 6;
    const int lm  = l & 15;
    const int lg  = l >> 4;
    const int lko = lg * 8;

    const unsigned short* vtb = vt + (size_t)(b * NH_ + kh) * HD_ * S_;

    bf16x8 qf[4];
    {
        const size_t qrow = (size_t)(b * S_ + sb * 64 + w * 16 + lm) * NQKV + qh * HD_;
        #pragma unroll
        for (int kk = 0; kk < 4; ++kk)
            qf[kk] = *(const bf16x8*)(qkv + qrow + kk * 32 + lko);
    }

    f32x4 acc_o[8];
    #pragma unroll
    for (int i = 0; i < 8; ++i) acc_o[i] = (f32x4){0.f, 0.f, 0.f, 0.f};
    float mreg[4], lreg[4];
    #pragma unroll
    for (int r = 0; r < 4; ++r) { mreg[r] = -1e30f; lreg[r] = 0.f; }

    const float sm_scale = 0.08838834764831845f;

    for (int c = 0; c <= sb; ++c) {
        __syncthreads();
        { // stage K [key][h]
            const int key = t >> 2, seg = t & 3;
            const size_t g = (size_t)(b * S_ + c * 64 + key) * NQKV + KOFF + kh * HD_ + seg * 32;
            const uint4* ksrc = (const uint4*)(qkv + g);
            #pragma unroll
            for (int i = 0; i < 4; ++i)
                *(uint4*)&k_s[key][seg * 32 + i * 8] = ksrc[i];
        }
        { // stage V^T [h][key] from pre-transposed global — no shuffles
            const int h  = t >> 1;
            const int ko = (t & 1) * 32;
            const unsigned short* src = vtb + (size_t)h * S_ + c * 64 + ko;
            #pragma unroll
            for (int i = 0; i < 4; ++i)
                *(uint4*)&v_t[h][ko + i * 8] = *(const uint4*)(src + i * 8);
        }
        __syncthreads();

        // ---- QK^T ----
        f32x4 acc_s[4];
        #pragma unroll
        for (int t4 = 0; t4 < 4; ++t4) acc_s[t4] = (f32x4){0.f, 0.f, 0.f, 0.f};
        #pragma unroll
        for (int kk = 0; kk < 4; ++kk) {
            const bf16x8 a = qf[kk];
            bf16x8 bv0 = *(const bf16x8*)&k_s[0 * 16 + lm][kk * 32 + lko];
            bf16x8 bv1 = *(const bf16x8*)&k_s[1 * 16 + lm][kk * 32 + lko];
            bf16x8 bv2 = *(const bf16x8*)&k_s[2 * 16 + lm][kk * 32 + lko];
            bf16x8 bv3 = *(const bf16x8*)&k_s[3 * 16 + lm][kk * 32 + lko];
            __builtin_amdgcn_s_setprio(1);
            acc_s[0] = __builtin_amdgcn_mfma_f32_16x16x32_bf16(a, bv0, acc_s[0], 0, 0, 0);
            acc_s[1] = __builtin_amdgcn_mfma_f32_16x16x32_bf16(a, bv1, acc_s[1], 0, 0, 0);
            acc_s[2] = __builtin_amdgcn_mfma_f32_16x16x32_bf16(a, bv2, acc_s[2], 0, 0, 0);
            acc_s[3] = __builtin_amdgcn_mfma_f32_16x16x32_bf16(a, bv3, acc_s[3], 0, 0, 0);
            __builtin_amdgcn_s_setprio(0);
        }

        // ---- online softmax with defer-max (THR=8) ----
        const bool diag = (c == sb);
        float sc[4][4];
        #pragma unroll
        for (int t4 = 0; t4 < 4; ++t4)
            #pragma unroll
            for (int r = 0; r < 4; ++r) {
                float s = acc_s[t4][r] * sm_scale;
                if (diag && (t4 * 16 + lm > w * 16 + lg * 4 + r)) s = -1e30f;
                sc[t4][r] = s;
            }
        #pragma unroll
        for (int r = 0; r < 4; ++r) {
            float mc = fmaxf(fmaxf(sc[0][r], sc[1][r]), fmaxf(sc[2][r], sc[3][r]));
            #pragma unroll
            for (int off = 1; off < 16; off <<= 1) mc = fmaxf(mc, __shfl_xor(mc, off, 64));
            if (mc > mreg[r] + 8.0f) {   // uniform within the 16-lane row group
                const float sf = __expf(mreg[r] - mc);
                mreg[r] = mc;
                lreg[r] *= sf;
                #pragma unroll
                for (int ht = 0; ht < 8; ++ht) acc_o[ht][r] *= sf;
            }
            float pv[4];
            #pragma unroll
            for (int t4 = 0; t4 < 4; ++t4) pv[t4] = __expf(sc[t4][r] - mreg[r]);
            float ps = pv[0] + pv[1] + pv[2] + pv[3];
            #pragma unroll
            for (int off = 1; off < 16; off <<= 1) ps += __shfl_xor(ps, off, 64);
            lreg[r] += ps;
            #pragma unroll
            for (int t4 = 0; t4 < 4; ++t4) {
                const float po = __shfl_xor(pv[t4], 1);
                if (!(l & 1)) {
                    unsigned int packed = (unsigned int)f2bf(pv[t4])
                                        | ((unsigned int)f2bf(po) << 16);
                    *(unsigned int*)&p_s[w][lg * 4 + r][t4 * 16 + lm] = packed;
                }
            }
        }

        // ---- PV ----
        #pragma unroll
        for (int kk = 0; kk < 2; ++kk) {
            const bf16x8 pa = *(const bf16x8*)&p_s[w][lm][kk * 32 + lko];
            #pragma unroll
            for (int ht = 0; ht < 8; ht += 4) {
                bf16x8 bv0 = *(const bf16x8*)&v_t[(ht + 0) * 16 + lm][kk * 32 + lko];
                bf16x8 bv1 = *(const bf16x8*)&v_t[(ht + 1) * 16 + lm][kk * 32 + lko];
                bf16x8 bv2 = *(const bf16x8*)&v_t[(ht + 2) * 16 + lm][kk * 32 + lko];
                bf16x8 bv3 = *(const bf16x8*)&v_t[(ht + 3) * 16 + lm][kk * 32 + lko];
                __builtin_amdgcn_s_setprio(1);
                acc_o[ht + 0] = __builtin_amdgcn_mfma_f32_16x16x32_bf16(pa, bv0, acc_o[ht + 0], 0, 0, 0);
                acc_o[ht + 1] = __builtin_amdgcn_mfma_f32_16x16x32_bf16(pa, bv1, acc_o[ht + 1], 0, 0, 0);
                acc_o[ht + 2] = __builtin_amdgcn_mfma_f32_16x16x32_bf16(pa, bv2, acc_o[ht + 2], 0, 0, 0);
                acc_o[ht + 3] = __builtin_amdgcn_mfma_f32_16x16x32_bf16(pa, bv3, acc_o[ht + 3], 0, 0, 0);
                __builtin_amdgcn_s_setprio(0);
            }
        }
    }

    #pragma unroll
    for (int r = 0; r < 4; ++r) {
        const float invl = 1.f / lreg[r];
        const size_t row = (size_t)(b * S_ + sb * 64 + w * 16 + lg * 4 + r);
        #pragma unroll
        for (int ht = 0; ht < 8; ++ht)
            ao[(row * QH_ + qh) * HD_ + ht * 16 + lm] = f2bf(acc_o[ht][r] * invl);
    }
}

// ---------------------------------------------------------------------------
extern "C" void kernel_launch(void* const* d_in, const int* in_sizes, int n_in,
                              void* d_out, int out_size, void* d_ws, size_t ws_size,
                              hipStream_t stream)
{
    const float* x  = (const float*)d_in[0];
    const int*  pos = (const int*)d_in[1];
    const float* Wq = (const float*)d_in[2];
    const float* Wk = (const float*)d_in[3];
    const float* Wv = (const float*)d_in[4];
    const float* Wo = (const float*)d_in[5];
    float* out = (float*)d_out;

    char* wsb = (char*)d_ws;
    unsigned short* qkv = (unsigned short*)(wsb);              // 48 MiB [4096][6144]
    unsigned short* wt  = (unsigned short*)(wsb + 50331648);   // Wt_qkv 48M -> Wt_o 32M
    unsigned short* vt  = (unsigned short*)(wsb + 83886080);   // 8 MiB V^T (after QKV gemm)
    unsigned short* r0  = (unsigned short*)(wsb + 100663296);  // 32 MiB x_bf -> ao

    const dim3 blk(256);
    convert_bf16_kernel<<<8192, blk, 0, stream>>>(x, r0);
    transpose_conv_kernel<<<dim3(2, 64, 32), blk, 0, stream>>>(Wq, wt, D_, HD_);
    transpose_conv_kernel<<<dim3(2, 64, 8),  blk, 0, stream>>>(Wk, wt + (size_t)KOFF * D_, D_, HD_);
    transpose_conv_kernel<<<dim3(2, 64, 8),  blk, 0, stream>>>(Wv, wt + (size_t)VOFF * D_, D_, HD_);
    // fused QKV projection
    gemm_bt_kernel<0><<<dim3(NQKV / 128, MROWS / 128), blk, 0, stream>>>(r0, wt, qkv, NQKV, D_);
    // Wo -> Wt_o (reuses wt region), V slab -> vt
    transpose_conv_kernel<<<dim3(64, 64, 1), blk, 0, stream>>>(Wo, wt, D_, D_);
    transpose_v_kernel<<<dim3(2, 32, 16), blk, 0, stream>>>(qkv, vt);
    // RoPE on Q and K slabs
    rope_kernel<5><<<(MROWS * QH_ * 64) / 256, blk, 0, stream>>>(qkv, pos);
    rope_kernel<3><<<(MROWS * NH_ * 64) / 256, blk, 0, stream>>>(qkv + KOFF, pos);
    // attention -> ao (reuses r0)
    attn_kernel<<<B_ * QH_ * (S_ / 64), blk, 0, stream>>>(qkv, vt, r0);
    // output projection -> fp32 out
    gemm_bt_kernel<1><<<dim3(D_ / 128, MROWS / 128), blk, 0, stream>>>(r0, wt, out, D_, QH_ * HD_);
}

// Round 5
// 704.646 us; speedup vs baseline: 10.5256x; 1.1275x over previous
//
#include <hip/hip_runtime.h>
#include <cstdint>
#include <cstddef>

#define B_  2
#define S_  2048
#define D_  4096
#define QH_ 32
#define NH_ 8
#define HD_ 128
#define MROWS (B_ * S_)                      // 4096
#define NQKV  (QH_ * HD_ + 2 * NH_ * HD_)    // 6144
#define KOFF  (QH_ * HD_)                    // 4096
#define VOFF  (QH_ * HD_ + NH_ * HD_)        // 5120

typedef __attribute__((ext_vector_type(8))) short bf16x8;
typedef __attribute__((ext_vector_type(4))) float f32x4;

__device__ __forceinline__ unsigned short f2bf(float f) {
    unsigned int u = __float_as_uint(f);
    return (unsigned short)((u + 0x7FFFu + ((u >> 16) & 1u)) >> 16);
}
__device__ __forceinline__ float bf2f(unsigned short h) { return __uint_as_float(((unsigned int)h) << 16); }

__device__ __forceinline__ void gl2lds16(const void* g, void* l) {
    __builtin_amdgcn_global_load_lds(
        (const __attribute__((address_space(1))) void*)g,
        (__attribute__((address_space(3))) void*)l, 16, 0, 0);
}

// ---------------------------------------------------------------------------
// fp32 -> bf16 straight convert (x). 8 elems/thread.
// ---------------------------------------------------------------------------
__global__ __launch_bounds__(256)
void convert_bf16_kernel(const float* __restrict__ in, unsigned short* __restrict__ out)
{
    const size_t i = ((size_t)blockIdx.x * 256 + threadIdx.x) * 8;
    float4 a = *(const float4*)(in + i);
    float4 b = *(const float4*)(in + i + 4);
    uint4 o;
    o.x = (unsigned int)f2bf(a.x) | ((unsigned int)f2bf(a.y) << 16);
    o.y = (unsigned int)f2bf(a.z) | ((unsigned int)f2bf(a.w) << 16);
    o.z = (unsigned int)f2bf(b.x) | ((unsigned int)f2bf(b.y) << 16);
    o.w = (unsigned int)f2bf(b.z) | ((unsigned int)f2bf(b.w) << 16);
    *(uint4*)(out + i) = o;
}

// ---------------------------------------------------------------------------
// Tile transpose-convert: in fp32 [R][C] (slab z) -> out bf16 [C][R]
// ---------------------------------------------------------------------------
__global__ __launch_bounds__(256)
void transpose_conv_kernel(const float* __restrict__ in, unsigned short* __restrict__ out,
                           int R, int C)
{
    __shared__ unsigned short tile[64][72];
    const int t  = threadIdx.x;
    const int c0 = blockIdx.x * 64;
    const int r0 = blockIdx.y * 64;
    in  += (size_t)blockIdx.z * R * C;
    out += (size_t)blockIdx.z * R * C;
    {
        const int rr = t >> 4;
        const int cc = (t & 15) * 4;
        #pragma unroll
        for (int p = 0; p < 4; ++p) {
            float4 v = *(const float4*)(in + (size_t)(r0 + p * 16 + rr) * C + c0 + cc);
            unsigned int lo = (unsigned int)f2bf(v.x) | ((unsigned int)f2bf(v.y) << 16);
            unsigned int hi = (unsigned int)f2bf(v.z) | ((unsigned int)f2bf(v.w) << 16);
            *(uint2*)&tile[p * 16 + rr][cc] = make_uint2(lo, hi);
        }
    }
    __syncthreads();
    {
        const int j  = t >> 3;
        const int i8 = (t & 7) * 8;
        #pragma unroll
        for (int p = 0; p < 2; ++p) {
            unsigned short tmp[8];
            #pragma unroll
            for (int e = 0; e < 8; ++e) tmp[e] = tile[i8 + e][p * 32 + j];
            *(uint4*)(out + (size_t)(c0 + p * 32 + j) * R + r0 + i8) = *(uint4*)tmp;
        }
    }
}

// ---------------------------------------------------------------------------
// bf16 transpose of the V slab of qkv: -> vt[(b*8+kh)*128 + h][2048 s]
// ---------------------------------------------------------------------------
__global__ __launch_bounds__(256)
void transpose_v_kernel(const unsigned short* __restrict__ qkv, unsigned short* __restrict__ vt)
{
    __shared__ unsigned short tile[64][76];
    const int t  = threadIdx.x;
    const int z  = blockIdx.z;            // b*8+kh
    const int b  = z >> 3, kh = z & 7;
    const int h0 = blockIdx.x * 64;
    const int s0 = blockIdx.y * 64;
    const unsigned short* in = qkv + (size_t)(b * S_) * NQKV + VOFF + kh * HD_;
    unsigned short* outb = vt + (size_t)z * HD_ * S_;
    {
        const int rr = t >> 4;            // s-local
        const int cc = (t & 15) * 4;      // h-local
        #pragma unroll
        for (int p = 0; p < 4; ++p) {
            uint2 v = *(const uint2*)(in + (size_t)(s0 + p * 16 + rr) * NQKV + h0 + cc);
            *(uint2*)&tile[p * 16 + rr][cc] = v;
        }
    }
    __syncthreads();
    {
        const int j  = t >> 3;            // h-local 0..31
        const int i8 = (t & 7) * 8;       // s-local
        #pragma unroll
        for (int p = 0; p < 2; ++p) {
            unsigned short tmp[8];
            #pragma unroll
            for (int e = 0; e < 8; ++e) tmp[e] = tile[i8 + e][p * 32 + j];
            *(uint4*)(outb + (size_t)(h0 + p * 32 + j) * S_ + s0 + i8) = *(uint4*)tmp;
        }
    }
}

// ---------------------------------------------------------------------------
// m97-structure GEMM: C[M,N] = A[M,K] * Bt[N,K]^T, bf16 operands, XCD swizzle.
// ---------------------------------------------------------------------------
template<int CF32>
__global__ __launch_bounds__(256)
void gemm_bt_kernel(const unsigned short* __restrict__ A,
                    const unsigned short* __restrict__ Bt,
                    void* __restrict__ Cp, int Nst, int K)
{
    __shared__ alignas(16) unsigned short As[128][64];
    __shared__ alignas(16) unsigned short Bs[128][64];
    const int t  = threadIdx.x, l = t & 63, w = t >> 6;
    const int gx  = gridDim.x;
    const int nwg = gx * gridDim.y;
    int lin = blockIdx.y * gx + blockIdx.x;
    lin = (lin & 7) * (nwg >> 3) + (lin >> 3);
    const int bn = (lin % gx) * 128, bm = (lin / gx) * 128;
    const int wr = w >> 1, wc = w & 1, lm = l & 15, lko = (l >> 4) * 8;

    f32x4 acc[4][4];
    #pragma unroll
    for (int i = 0; i < 4; ++i)
        #pragma unroll
        for (int j = 0; j < 4; ++j) acc[i][j] = (f32x4){0.f, 0.f, 0.f, 0.f};

    const int srow = w * 8 + (l >> 3);
    const int scol = (l & 7) * 8;
    const unsigned short* Ab = A  + (size_t)(bm + srow) * K + scol;
    const unsigned short* Bb = Bt + (size_t)(bn + srow) * K + scol;
    char* AsB = (char*)&As[0][0] + w * 1024;
    char* BsB = (char*)&Bs[0][0] + w * 1024;

    for (int kt = 0; kt < K; kt += 64) {
        __syncthreads();
        #pragma unroll
        for (int c = 0; c < 4; ++c) {
            gl2lds16(Ab + (size_t)(c * 32) * K + kt, AsB + c * 4096);
            gl2lds16(Bb + (size_t)(c * 32) * K + kt, BsB + c * 4096);
        }
        __syncthreads();
        #pragma unroll
        for (int kk = 0; kk < 64; kk += 32) {
            bf16x8 af[4], bv[4];
            #pragma unroll
            for (int i = 0; i < 4; ++i) af[i] = *(const bf16x8*)&As[wr * 64 + i * 16 + lm][kk + lko];
            #pragma unroll
            for (int j = 0; j < 4; ++j) bv[j] = *(const bf16x8*)&Bs[wc * 64 + j * 16 + lm][kk + lko];
            __builtin_amdgcn_s_setprio(1);
            #pragma unroll
            for (int i = 0; i < 4; ++i)
                #pragma unroll
                for (int j = 0; j < 4; ++j)
                    acc[i][j] = __builtin_amdgcn_mfma_f32_16x16x32_bf16(af[i], bv[j], acc[i][j], 0, 0, 0);
            __builtin_amdgcn_s_setprio(0);
        }
    }
    const int lr4 = (l >> 4) * 4;
    #pragma unroll
    for (int i = 0; i < 4; ++i) {
        #pragma unroll
        for (int j = 0; j < 4; ++j) {
            int row = bm + wr * 64 + i * 16 + lr4;
            int col = bn + wc * 64 + j * 16 + lm;
            #pragma unroll
            for (int jj = 0; jj < 4; ++jj) {
                if constexpr (CF32)
                    ((float*)Cp)[(size_t)(row + jj) * Nst + col] = acc[i][j][jj];
                else
                    ((unsigned short*)Cp)[(size_t)(row + jj) * Nst + col] = f2bf(acc[i][j][jj]);
            }
        }
    }
}

// ---------------------------------------------------------------------------
// RoPE in-place on a slab of qkv (row stride NQKV).
// ---------------------------------------------------------------------------
template<int LOG2H>
__global__ __launch_bounds__(256)
void rope_kernel(unsigned short* __restrict__ data, const int* __restrict__ positions)
{
    const int gid  = blockIdx.x * 256 + threadIdx.x;
    const int j    = gid & 63;
    const int hr   = gid >> 6;
    const int head = hr & ((1 << LOG2H) - 1);
    const int bs   = hr >> LOG2H;
    const float pos = (float)positions[bs];
    const float inv = expf(-0.14391156831f * (float)j);
    float s, c;
    sincosf(pos * inv, &s, &c);
    const size_t base = (size_t)bs * NQKV + head * HD_;
    const float x1 = bf2f(data[base + j]);
    const float x2 = bf2f(data[base + 64 + j]);
    data[base + j]      = f2bf(x1 * c - x2 * s);
    data[base + 64 + j] = f2bf(x2 * c + x1 * s);
}

// ---------------------------------------------------------------------------
// MFMA flash attention, swapped-QK^T in-register softmax.
//   QK^T computed as mfma(K_frag, Q_frag) -> S^T: col(lane&15)=q-row,
//   row((lane>>4)*4+reg)=key. Lane owns 16 scores of ONE q-row -> row
//   reduce = local + 2 shfl; P written to LDS in PV-A layout by owner lane.
// ---------------------------------------------------------------------------
__global__ __launch_bounds__(256)
void attn_kernel(const unsigned short* __restrict__ qkv,
                 const unsigned short* __restrict__ vt,
                 unsigned short* __restrict__ ao)
{
    constexpr int LDK = 136;
    constexpr int LDV = 72;
    __shared__ alignas(16) unsigned short k_s[64][LDK];
    __shared__ alignas(16) unsigned short v_t[128][LDV];
    __shared__ alignas(16) unsigned short p_s[4][16][LDV];

    const int t   = threadIdx.x;
    const int blk = blockIdx.x;
    const int sb  = 31 - (blk >> 6);     // heavy (sb=31) blocks launch first
    const int pr  = blk & 63;
    const int qh  = pr >> 1;
    const int b   = pr & 1;
    const int kh  = qh >> 2;
    const int l   = t & 63, w = t >> 6;
    const int lm  = l & 15;
    const int lg  = l >> 4;
    const int lg4 = lg * 4;
    const int lko = lg * 8;
    const int wrow = w * 16 + lm;        // this lane's q-row (block-local)

    const unsigned short* vtb = vt + (size_t)(b * NH_ + kh) * HD_ * S_;

    bf16x8 qf[4];
    {
        const size_t qrow = (size_t)(b * S_ + sb * 64 + wrow) * NQKV + qh * HD_;
        #pragma unroll
        for (int kk = 0; kk < 4; ++kk)
            qf[kk] = *(const bf16x8*)(qkv + qrow + kk * 32 + lko);
    }

    f32x4 acc_o[8];
    #pragma unroll
    for (int i = 0; i < 8; ++i) acc_o[i] = (f32x4){0.f, 0.f, 0.f, 0.f};
    float mreg = -1e30f, lreg = 0.f;     // state for q-row `wrow` (x4 replicated)

    const float sm_scale = 0.08838834764831845f;

    for (int c = 0; c <= sb; ++c) {
        __syncthreads();
        { // stage K [key][h]
            const int key = t >> 2, seg = t & 3;
            const size_t g = (size_t)(b * S_ + c * 64 + key) * NQKV + KOFF + kh * HD_ + seg * 32;
            const uint4* ksrc = (const uint4*)(qkv + g);
            #pragma unroll
            for (int i = 0; i < 4; ++i)
                *(uint4*)&k_s[key][seg * 32 + i * 8] = ksrc[i];
        }
        { // stage V^T [h][key] from pre-transposed global
            const int h  = t >> 1;
            const int ko = (t & 1) * 32;
            const unsigned short* src = vtb + (size_t)h * S_ + c * 64 + ko;
            #pragma unroll
            for (int i = 0; i < 4; ++i)
                *(uint4*)&v_t[h][ko + i * 8] = *(const uint4*)(src + i * 8);
        }
        __syncthreads();

        // ---- QK^T swapped: acc_s[t4][r] = S[key=t4*16+lg4+r][qrow=wrow] ----
        f32x4 acc_s[4];
        #pragma unroll
        for (int t4 = 0; t4 < 4; ++t4) acc_s[t4] = (f32x4){0.f, 0.f, 0.f, 0.f};
        #pragma unroll
        for (int kk = 0; kk < 4; ++kk) {
            const bf16x8 qv = qf[kk];
            bf16x8 kf0 = *(const bf16x8*)&k_s[0 * 16 + lm][kk * 32 + lko];
            bf16x8 kf1 = *(const bf16x8*)&k_s[1 * 16 + lm][kk * 32 + lko];
            bf16x8 kf2 = *(const bf16x8*)&k_s[2 * 16 + lm][kk * 32 + lko];
            bf16x8 kf3 = *(const bf16x8*)&k_s[3 * 16 + lm][kk * 32 + lko];
            __builtin_amdgcn_s_setprio(1);
            acc_s[0] = __builtin_amdgcn_mfma_f32_16x16x32_bf16(kf0, qv, acc_s[0], 0, 0, 0);
            acc_s[1] = __builtin_amdgcn_mfma_f32_16x16x32_bf16(kf1, qv, acc_s[1], 0, 0, 0);
            acc_s[2] = __builtin_amdgcn_mfma_f32_16x16x32_bf16(kf2, qv, acc_s[2], 0, 0, 0);
            acc_s[3] = __builtin_amdgcn_mfma_f32_16x16x32_bf16(kf3, qv, acc_s[3], 0, 0, 0);
            __builtin_amdgcn_s_setprio(0);
        }

        // ---- in-register online softmax for q-row `wrow` ----
        const bool diag = (c == sb);
        float p[4][4];
        #pragma unroll
        for (int t4 = 0; t4 < 4; ++t4)
            #pragma unroll
            for (int r = 0; r < 4; ++r) {
                float s = acc_s[t4][r] * sm_scale;
                if (diag && (t4 * 16 + lg4 + r > wrow)) s = -1e30f;
                p[t4][r] = s;
            }
        float mc = p[0][0];
        #pragma unroll
        for (int t4 = 0; t4 < 4; ++t4)
            #pragma unroll
            for (int r = 0; r < 4; ++r) mc = fmaxf(mc, p[t4][r]);
        mc = fmaxf(mc, __shfl_xor(mc, 16, 64));
        mc = fmaxf(mc, __shfl_xor(mc, 32, 64));
        float sf = 1.0f;
        if (mc > mreg + 8.0f) {          // defer-max (THR=8)
            sf = __expf(mreg - mc);
            mreg = mc;
            lreg *= sf;
        }
        if (__any(sf != 1.0f)) {         // rescale O (rare): bcast sf per out-row
            #pragma unroll
            for (int r = 0; r < 4; ++r) {
                const float s_r = __shfl(sf, (l & 48) | (lg4 + r), 64);
                #pragma unroll
                for (int ht = 0; ht < 8; ++ht) acc_o[ht][r] *= s_r;
            }
        }
        float ps = 0.f;
        #pragma unroll
        for (int t4 = 0; t4 < 4; ++t4)
            #pragma unroll
            for (int r = 0; r < 4; ++r) {
                p[t4][r] = __expf(p[t4][r] - mreg);
                ps += p[t4][r];
            }
        ps += __shfl_xor(ps, 16, 64);
        ps += __shfl_xor(ps, 32, 64);
        lreg += ps;
        // P -> p_s[w][qrow=lm][key], keys t4*16+lg4+{0..3} contiguous
        #pragma unroll
        for (int t4 = 0; t4 < 4; ++t4) {
            unsigned int d0 = (unsigned int)f2bf(p[t4][0]) | ((unsigned int)f2bf(p[t4][1]) << 16);
            unsigned int d1 = (unsigned int)f2bf(p[t4][2]) | ((unsigned int)f2bf(p[t4][3]) << 16);
            *(unsigned int*)&p_s[w][lm][t4 * 16 + lg4]     = d0;
            *(unsigned int*)&p_s[w][lm][t4 * 16 + lg4 + 2] = d1;
        }

        // ---- PV (unchanged): D col=h-tile, row=lg4+r=qrow ----
        #pragma unroll
        for (int kk = 0; kk < 2; ++kk) {
            const bf16x8 pa = *(const bf16x8*)&p_s[w][lm][kk * 32 + lko];
            #pragma unroll
            for (int ht = 0; ht < 8; ht += 4) {
                bf16x8 bv0 = *(const bf16x8*)&v_t[(ht + 0) * 16 + lm][kk * 32 + lko];
                bf16x8 bv1 = *(const bf16x8*)&v_t[(ht + 1) * 16 + lm][kk * 32 + lko];
                bf16x8 bv2 = *(const bf16x8*)&v_t[(ht + 2) * 16 + lm][kk * 32 + lko];
                bf16x8 bv3 = *(const bf16x8*)&v_t[(ht + 3) * 16 + lm][kk * 32 + lko];
                __builtin_amdgcn_s_setprio(1);
                acc_o[ht + 0] = __builtin_amdgcn_mfma_f32_16x16x32_bf16(pa, bv0, acc_o[ht + 0], 0, 0, 0);
                acc_o[ht + 1] = __builtin_amdgcn_mfma_f32_16x16x32_bf16(pa, bv1, acc_o[ht + 1], 0, 0, 0);
                acc_o[ht + 2] = __builtin_amdgcn_mfma_f32_16x16x32_bf16(pa, bv2, acc_o[ht + 2], 0, 0, 0);
                acc_o[ht + 3] = __builtin_amdgcn_mfma_f32_16x16x32_bf16(pa, bv3, acc_o[ht + 3], 0, 0, 0);
                __builtin_amdgcn_s_setprio(0);
            }
        }
    }

    // ---- epilogue: fetch l for out rows lg4+r, normalize, store ----
    #pragma unroll
    for (int r = 0; r < 4; ++r) {
        const float lr = __shfl(lreg, (l & 48) | (lg4 + r), 64);
        const float invl = 1.f / lr;
        const size_t row = (size_t)(b * S_ + sb * 64 + w * 16 + lg4 + r);
        #pragma unroll
        for (int ht = 0; ht < 8; ++ht)
            ao[(row * QH_ + qh) * HD_ + ht * 16 + lm] = f2bf(acc_o[ht][r] * invl);
    }
}

// ---------------------------------------------------------------------------
extern "C" void kernel_launch(void* const* d_in, const int* in_sizes, int n_in,
                              void* d_out, int out_size, void* d_ws, size_t ws_size,
                              hipStream_t stream)
{
    const float* x  = (const float*)d_in[0];
    const int*  pos = (const int*)d_in[1];
    const float* Wq = (const float*)d_in[2];
    const float* Wk = (const float*)d_in[3];
    const float* Wv = (const float*)d_in[4];
    const float* Wo = (const float*)d_in[5];
    float* out = (float*)d_out;

    char* wsb = (char*)d_ws;
    unsigned short* qkv = (unsigned short*)(wsb);              // 48 MiB [4096][6144]
    unsigned short* wt  = (unsigned short*)(wsb + 50331648);   // Wt_qkv 48M -> Wt_o 32M
    unsigned short* vt  = (unsigned short*)(wsb + 83886080);   // 8 MiB V^T
    unsigned short* r0  = (unsigned short*)(wsb + 100663296);  // 32 MiB x_bf -> ao

    const dim3 blk(256);
    convert_bf16_kernel<<<8192, blk, 0, stream>>>(x, r0);
    transpose_conv_kernel<<<dim3(2, 64, 32), blk, 0, stream>>>(Wq, wt, D_, HD_);
    transpose_conv_kernel<<<dim3(2, 64, 8),  blk, 0, stream>>>(Wk, wt + (size_t)KOFF * D_, D_, HD_);
    transpose_conv_kernel<<<dim3(2, 64, 8),  blk, 0, stream>>>(Wv, wt + (size_t)VOFF * D_, D_, HD_);
    gemm_bt_kernel<0><<<dim3(NQKV / 128, MROWS / 128), blk, 0, stream>>>(r0, wt, qkv, NQKV, D_);
    transpose_conv_kernel<<<dim3(64, 64, 1), blk, 0, stream>>>(Wo, wt, D_, D_);
    transpose_v_kernel<<<dim3(2, 32, 16), blk, 0, stream>>>(qkv, vt);
    rope_kernel<5><<<(MROWS * QH_ * 64) / 256, blk, 0, stream>>>(qkv, pos);
    rope_kernel<3><<<(MROWS * NH_ * 64) / 256, blk, 0, stream>>>(qkv + KOFF, pos);
    attn_kernel<<<B_ * QH_ * (S_ / 64), blk, 0, stream>>>(qkv, vt, r0);
    gemm_bt_kernel<1><<<dim3(D_ / 128, MROWS / 128), blk, 0, stream>>>(r0, wt, out, D_, QH_ * HD_);
}

// Round 6
// 607.195 us; speedup vs baseline: 12.2149x; 1.1605x over previous
//
#include <hip/hip_runtime.h>
#include <cstdint>
#include <cstddef>

#define B_  2
#define S_  2048
#define D_  4096
#define QH_ 32
#define NH_ 8
#define HD_ 128
#define MROWS (B_ * S_)                      // 4096
#define NQKV  (QH_ * HD_ + 2 * NH_ * HD_)    // 6144
#define KOFF  (QH_ * HD_)                    // 4096
#define VOFF  (QH_ * HD_ + NH_ * HD_)        // 5120

typedef __attribute__((ext_vector_type(8))) short bf16x8;
typedef __attribute__((ext_vector_type(4))) float f32x4;

__device__ __forceinline__ unsigned short f2bf(float f) {
    unsigned int u = __float_as_uint(f);
    return (unsigned short)((u + 0x7FFFu + ((u >> 16) & 1u)) >> 16);
}
__device__ __forceinline__ float bf2f(unsigned short h) { return __uint_as_float(((unsigned int)h) << 16); }

__device__ __forceinline__ void gl2lds16(const void* g, void* l) {
    __builtin_amdgcn_global_load_lds(
        (const __attribute__((address_space(1))) void*)g,
        (__attribute__((address_space(3))) void*)l, 16, 0, 0);
}

// ---------------------------------------------------------------------------
// fp32 -> bf16 straight convert (x). 8 elems/thread.
// ---------------------------------------------------------------------------
__global__ __launch_bounds__(256)
void convert_bf16_kernel(const float* __restrict__ in, unsigned short* __restrict__ out)
{
    const size_t i = ((size_t)blockIdx.x * 256 + threadIdx.x) * 8;
    float4 a = *(const float4*)(in + i);
    float4 b = *(const float4*)(in + i + 4);
    uint4 o;
    o.x = (unsigned int)f2bf(a.x) | ((unsigned int)f2bf(a.y) << 16);
    o.y = (unsigned int)f2bf(a.z) | ((unsigned int)f2bf(a.w) << 16);
    o.z = (unsigned int)f2bf(b.x) | ((unsigned int)f2bf(b.y) << 16);
    o.w = (unsigned int)f2bf(b.z) | ((unsigned int)f2bf(b.w) << 16);
    *(uint4*)(out + i) = o;
}

// ---------------------------------------------------------------------------
// Tile transpose-convert: in fp32 [R][C] (slab z) -> out bf16 [C][R]
// ---------------------------------------------------------------------------
__global__ __launch_bounds__(256)
void transpose_conv_kernel(const float* __restrict__ in, unsigned short* __restrict__ out,
                           int R, int C)
{
    __shared__ unsigned short tile[64][72];
    const int t  = threadIdx.x;
    const int c0 = blockIdx.x * 64;
    const int r0 = blockIdx.y * 64;
    in  += (size_t)blockIdx.z * R * C;
    out += (size_t)blockIdx.z * R * C;
    {
        const int rr = t >> 4;
        const int cc = (t & 15) * 4;
        #pragma unroll
        for (int p = 0; p < 4; ++p) {
            float4 v = *(const float4*)(in + (size_t)(r0 + p * 16 + rr) * C + c0 + cc);
            unsigned int lo = (unsigned int)f2bf(v.x) | ((unsigned int)f2bf(v.y) << 16);
            unsigned int hi = (unsigned int)f2bf(v.z) | ((unsigned int)f2bf(v.w) << 16);
            *(uint2*)&tile[p * 16 + rr][cc] = make_uint2(lo, hi);
        }
    }
    __syncthreads();
    {
        const int j  = t >> 3;
        const int i8 = (t & 7) * 8;
        #pragma unroll
        for (int p = 0; p < 2; ++p) {
            unsigned short tmp[8];
            #pragma unroll
            for (int e = 0; e < 8; ++e) tmp[e] = tile[i8 + e][p * 32 + j];
            *(uint4*)(out + (size_t)(c0 + p * 32 + j) * R + r0 + i8) = *(uint4*)tmp;
        }
    }
}

// ---------------------------------------------------------------------------
// bf16 transpose of the V slab of qkv: -> vt[(b*8+kh)*128 + h][2048 s]
// ---------------------------------------------------------------------------
__global__ __launch_bounds__(256)
void transpose_v_kernel(const unsigned short* __restrict__ qkv, unsigned short* __restrict__ vt)
{
    __shared__ unsigned short tile[64][76];
    const int t  = threadIdx.x;
    const int z  = blockIdx.z;            // b*8+kh
    const int b  = z >> 3, kh = z & 7;
    const int h0 = blockIdx.x * 64;
    const int s0 = blockIdx.y * 64;
    const unsigned short* in = qkv + (size_t)(b * S_) * NQKV + VOFF + kh * HD_;
    unsigned short* outb = vt + (size_t)z * HD_ * S_;
    {
        const int rr = t >> 4;            // s-local
        const int cc = (t & 15) * 4;      // h-local
        #pragma unroll
        for (int p = 0; p < 4; ++p) {
            uint2 v = *(const uint2*)(in + (size_t)(s0 + p * 16 + rr) * NQKV + h0 + cc);
            *(uint2*)&tile[p * 16 + rr][cc] = v;
        }
    }
    __syncthreads();
    {
        const int j  = t >> 3;            // h-local 0..31
        const int i8 = (t & 7) * 8;       // s-local
        #pragma unroll
        for (int p = 0; p < 2; ++p) {
            unsigned short tmp[8];
            #pragma unroll
            for (int e = 0; e < 8; ++e) tmp[e] = tile[i8 + e][p * 32 + j];
            *(uint4*)(outb + (size_t)(h0 + p * 32 + j) * S_ + s0 + i8) = *(uint4*)tmp;
        }
    }
}

// ---------------------------------------------------------------------------
// Deep-pipelined 256x256 GEMM: C[M,N] = A[M,K] * Bt[N,K]^T, bf16 operands.
// BK=32, triple-buffered LDS (96 KiB), raw s_barrier + counted vmcnt(4)
// (never 0 in main loop), 8 waves (2x4), per-wave 128x64, 2 phases/K-tile
// of 16 MFMA with setprio. Staging of tile t+2 issued during tile t.
// Race-safety: buf (t+2)%3 was last READ in tile t-1, which all waves
// finished before tile t's boundary barrier; loads issue after it.
// ---------------------------------------------------------------------------
template<int CF32>
__global__ __launch_bounds__(512, 2)
void gemm256_kernel(const unsigned short* __restrict__ A,
                    const unsigned short* __restrict__ Bt,
                    void* __restrict__ Cp, int Nst, int K)
{
    __shared__ alignas(16) unsigned short lds[3][2][256][32];  // 96 KiB

    const int t = threadIdx.x, l = t & 63, w = t >> 6;
    const int gx  = gridDim.x;
    const int nwg = gx * gridDim.y;
    int lin = blockIdx.y * gx + blockIdx.x;
    lin = (lin & 7) * (nwg >> 3) + (lin >> 3);       // bijective XCD swizzle (nwg%8==0)
    const int bn = (lin % gx) * 256, bm = (lin / gx) * 256;
    const int wr = w >> 2, wc = w & 3;               // 2 (M) x 4 (N) waves
    const int lm = l & 15, lg = l >> 4;

    f32x4 acc[8][4];
    #pragma unroll
    for (int i = 0; i < 8; ++i)
        #pragma unroll
        for (int j = 0; j < 4; ++j) acc[i][j] = (f32x4){0.f, 0.f, 0.f, 0.f};

    // staging: wave w covers rows {w*16..w*16+15} and {128+w*16..} of each operand
    const int srow = w * 16 + (l >> 2);
    const int scol = (l & 3) * 8;
    const unsigned short* Asrc = A  + (size_t)(bm + srow) * K + scol;
    const unsigned short* Bsrc = Bt + (size_t)(bn + srow) * K + scol;

    #define STAGE_A(tt, bb) do {                                                  \
        gl2lds16(Asrc + (size_t)(tt) * 32,                  &lds[bb][0][w*16][0]); \
        gl2lds16(Asrc + (size_t)128*K + (size_t)(tt) * 32,  &lds[bb][0][128 + w*16][0]); } while (0)
    #define STAGE_B(tt, bb) do {                                                  \
        gl2lds16(Bsrc + (size_t)(tt) * 32,                  &lds[bb][1][w*16][0]); \
        gl2lds16(Bsrc + (size_t)128*K + (size_t)(tt) * 32,  &lds[bb][1][128 + w*16][0]); } while (0)

    const int nkt = K >> 5;
    STAGE_A(0, 0); STAGE_B(0, 0);      // tile 0 -> buf 0
    STAGE_A(1, 1); STAGE_B(1, 1);      // tile 1 -> buf 1

    for (int kt = 0; kt < nkt; ++kt) {
        // boundary: tile kt resident after this (4 newest loads = tile kt+1)
        if (kt + 1 < nkt) asm volatile("s_waitcnt vmcnt(4)" ::: "memory");
        else              asm volatile("s_waitcnt vmcnt(0)" ::: "memory");
        asm volatile("s_barrier" ::: "memory");

        const unsigned short (*bufA)[32] = lds[kt % 3][0];
        const unsigned short (*bufB)[32] = lds[kt % 3][1];
        const int nb = (kt + 2) % 3;

        // ---- phase A: B-frags + A-frags 0-3, 16 MFMA ----
        bf16x8 bfr[4], afr[4];
        #pragma unroll
        for (int j = 0; j < 4; ++j) bfr[j] = *(const bf16x8*)&bufB[wc * 64 + j * 16 + lm][lg * 8];
        #pragma unroll
        for (int i = 0; i < 4; ++i) afr[i] = *(const bf16x8*)&bufA[wr * 128 + i * 16 + lm][lg * 8];
        if (kt + 2 < nkt) STAGE_A(kt + 2, nb);
        __builtin_amdgcn_s_setprio(1);
        #pragma unroll
        for (int i = 0; i < 4; ++i)
            #pragma unroll
            for (int j = 0; j < 4; ++j)
                acc[i][j] = __builtin_amdgcn_mfma_f32_16x16x32_bf16(afr[i], bfr[j], acc[i][j], 0, 0, 0);
        __builtin_amdgcn_s_setprio(0);
        asm volatile("s_barrier" ::: "memory");

        // ---- phase B: A-frags 4-7, 16 MFMA ----
        #pragma unroll
        for (int i = 0; i < 4; ++i) afr[i] = *(const bf16x8*)&bufA[wr * 128 + (i + 4) * 16 + lm][lg * 8];
        if (kt + 2 < nkt) STAGE_B(kt + 2, nb);
        __builtin_amdgcn_s_setprio(1);
        #pragma unroll
        for (int i = 0; i < 4; ++i)
            #pragma unroll
            for (int j = 0; j < 4; ++j)
                acc[i + 4][j] = __builtin_amdgcn_mfma_f32_16x16x32_bf16(afr[i], bfr[j], acc[i + 4][j], 0, 0, 0);
        __builtin_amdgcn_s_setprio(0);
        // boundary barrier at loop top doubles as phase-B end barrier
    }
    #undef STAGE_A
    #undef STAGE_B

    // C/D: col = lane&15, row = (lane>>4)*4 + reg
    const int lr4 = lg * 4;
    #pragma unroll
    for (int i = 0; i < 8; ++i) {
        #pragma unroll
        for (int j = 0; j < 4; ++j) {
            int row = bm + wr * 128 + i * 16 + lr4;
            int col = bn + wc * 64 + j * 16 + lm;
            #pragma unroll
            for (int jj = 0; jj < 4; ++jj) {
                if constexpr (CF32)
                    ((float*)Cp)[(size_t)(row + jj) * Nst + col] = acc[i][j][jj];
                else
                    ((unsigned short*)Cp)[(size_t)(row + jj) * Nst + col] = f2bf(acc[i][j][jj]);
            }
        }
    }
}

// ---------------------------------------------------------------------------
// RoPE in-place on a slab of qkv (row stride NQKV).
// ---------------------------------------------------------------------------
template<int LOG2H>
__global__ __launch_bounds__(256)
void rope_kernel(unsigned short* __restrict__ data, const int* __restrict__ positions)
{
    const int gid  = blockIdx.x * 256 + threadIdx.x;
    const int j    = gid & 63;
    const int hr   = gid >> 6;
    const int head = hr & ((1 << LOG2H) - 1);
    const int bs   = hr >> LOG2H;
    const float pos = (float)positions[bs];
    const float inv = expf(-0.14391156831f * (float)j);
    float s, c;
    sincosf(pos * inv, &s, &c);
    const size_t base = (size_t)bs * NQKV + head * HD_;
    const float x1 = bf2f(data[base + j]);
    const float x2 = bf2f(data[base + 64 + j]);
    data[base + j]      = f2bf(x1 * c - x2 * s);
    data[base + 64 + j] = f2bf(x2 * c + x1 * s);
}

// ---------------------------------------------------------------------------
// MFMA flash attention, swapped-QK^T in-register softmax (unchanged, passing).
// ---------------------------------------------------------------------------
__global__ __launch_bounds__(256)
void attn_kernel(const unsigned short* __restrict__ qkv,
                 const unsigned short* __restrict__ vt,
                 unsigned short* __restrict__ ao)
{
    constexpr int LDK = 136;
    constexpr int LDV = 72;
    __shared__ alignas(16) unsigned short k_s[64][LDK];
    __shared__ alignas(16) unsigned short v_t[128][LDV];
    __shared__ alignas(16) unsigned short p_s[4][16][LDV];

    const int t   = threadIdx.x;
    const int blk = blockIdx.x;
    const int sb  = 31 - (blk >> 6);
    const int pr  = blk & 63;
    const int qh  = pr >> 1;
    const int b   = pr & 1;
    const int kh  = qh >> 2;
    const int l   = t & 63, w = t >> 6;
    const int lm  = l & 15;
    const int lg  = l >> 4;
    const int lg4 = lg * 4;
    const int lko = lg * 8;
    const int wrow = w * 16 + lm;

    const unsigned short* vtb = vt + (size_t)(b * NH_ + kh) * HD_ * S_;

    bf16x8 qf[4];
    {
        const size_t qrow = (size_t)(b * S_ + sb * 64 + wrow) * NQKV + qh * HD_;
        #pragma unroll
        for (int kk = 0; kk < 4; ++kk)
            qf[kk] = *(const bf16x8*)(qkv + qrow + kk * 32 + lko);
    }

    f32x4 acc_o[8];
    #pragma unroll
    for (int i = 0; i < 8; ++i) acc_o[i] = (f32x4){0.f, 0.f, 0.f, 0.f};
    float mreg = -1e30f, lreg = 0.f;

    const float sm_scale = 0.08838834764831845f;

    for (int c = 0; c <= sb; ++c) {
        __syncthreads();
        {
            const int key = t >> 2, seg = t & 3;
            const size_t g = (size_t)(b * S_ + c * 64 + key) * NQKV + KOFF + kh * HD_ + seg * 32;
            const uint4* ksrc = (const uint4*)(qkv + g);
            #pragma unroll
            for (int i = 0; i < 4; ++i)
                *(uint4*)&k_s[key][seg * 32 + i * 8] = ksrc[i];
        }
        {
            const int h  = t >> 1;
            const int ko = (t & 1) * 32;
            const unsigned short* src = vtb + (size_t)h * S_ + c * 64 + ko;
            #pragma unroll
            for (int i = 0; i < 4; ++i)
                *(uint4*)&v_t[h][ko + i * 8] = *(const uint4*)(src + i * 8);
        }
        __syncthreads();

        f32x4 acc_s[4];
        #pragma unroll
        for (int t4 = 0; t4 < 4; ++t4) acc_s[t4] = (f32x4){0.f, 0.f, 0.f, 0.f};
        #pragma unroll
        for (int kk = 0; kk < 4; ++kk) {
            const bf16x8 qv = qf[kk];
            bf16x8 kf0 = *(const bf16x8*)&k_s[0 * 16 + lm][kk * 32 + lko];
            bf16x8 kf1 = *(const bf16x8*)&k_s[1 * 16 + lm][kk * 32 + lko];
            bf16x8 kf2 = *(const bf16x8*)&k_s[2 * 16 + lm][kk * 32 + lko];
            bf16x8 kf3 = *(const bf16x8*)&k_s[3 * 16 + lm][kk * 32 + lko];
            __builtin_amdgcn_s_setprio(1);
            acc_s[0] = __builtin_amdgcn_mfma_f32_16x16x32_bf16(kf0, qv, acc_s[0], 0, 0, 0);
            acc_s[1] = __builtin_amdgcn_mfma_f32_16x16x32_bf16(kf1, qv, acc_s[1], 0, 0, 0);
            acc_s[2] = __builtin_amdgcn_mfma_f32_16x16x32_bf16(kf2, qv, acc_s[2], 0, 0, 0);
            acc_s[3] = __builtin_amdgcn_mfma_f32_16x16x32_bf16(kf3, qv, acc_s[3], 0, 0, 0);
            __builtin_amdgcn_s_setprio(0);
        }

        const bool diag = (c == sb);
        float p[4][4];
        #pragma unroll
        for (int t4 = 0; t4 < 4; ++t4)
            #pragma unroll
            for (int r = 0; r < 4; ++r) {
                float s = acc_s[t4][r] * sm_scale;
                if (diag && (t4 * 16 + lg4 + r > wrow)) s = -1e30f;
                p[t4][r] = s;
            }
        float mc = p[0][0];
        #pragma unroll
        for (int t4 = 0; t4 < 4; ++t4)
            #pragma unroll
            for (int r = 0; r < 4; ++r) mc = fmaxf(mc, p[t4][r]);
        mc = fmaxf(mc, __shfl_xor(mc, 16, 64));
        mc = fmaxf(mc, __shfl_xor(mc, 32, 64));
        float sf = 1.0f;
        if (mc > mreg + 8.0f) {
            sf = __expf(mreg - mc);
            mreg = mc;
            lreg *= sf;
        }
        if (__any(sf != 1.0f)) {
            #pragma unroll
            for (int r = 0; r < 4; ++r) {
                const float s_r = __shfl(sf, (l & 48) | (lg4 + r), 64);
                #pragma unroll
                for (int ht = 0; ht < 8; ++ht) acc_o[ht][r] *= s_r;
            }
        }
        float ps = 0.f;
        #pragma unroll
        for (int t4 = 0; t4 < 4; ++t4)
            #pragma unroll
            for (int r = 0; r < 4; ++r) {
                p[t4][r] = __expf(p[t4][r] - mreg);
                ps += p[t4][r];
            }
        ps += __shfl_xor(ps, 16, 64);
        ps += __shfl_xor(ps, 32, 64);
        lreg += ps;
        #pragma unroll
        for (int t4 = 0; t4 < 4; ++t4) {
            unsigned int d0 = (unsigned int)f2bf(p[t4][0]) | ((unsigned int)f2bf(p[t4][1]) << 16);
            unsigned int d1 = (unsigned int)f2bf(p[t4][2]) | ((unsigned int)f2bf(p[t4][3]) << 16);
            *(unsigned int*)&p_s[w][lm][t4 * 16 + lg4]     = d0;
            *(unsigned int*)&p_s[w][lm][t4 * 16 + lg4 + 2] = d1;
        }

        #pragma unroll
        for (int kk = 0; kk < 2; ++kk) {
            const bf16x8 pa = *(const bf16x8*)&p_s[w][lm][kk * 32 + lko];
            #pragma unroll
            for (int ht = 0; ht < 8; ht += 4) {
                bf16x8 bv0 = *(const bf16x8*)&v_t[(ht + 0) * 16 + lm][kk * 32 + lko];
                bf16x8 bv1 = *(const bf16x8*)&v_t[(ht + 1) * 16 + lm][kk * 32 + lko];
                bf16x8 bv2 = *(const bf16x8*)&v_t[(ht + 2) * 16 + lm][kk * 32 + lko];
                bf16x8 bv3 = *(const bf16x8*)&v_t[(ht + 3) * 16 + lm][kk * 32 + lko];
                __builtin_amdgcn_s_setprio(1);
                acc_o[ht + 0] = __builtin_amdgcn_mfma_f32_16x16x32_bf16(pa, bv0, acc_o[ht + 0], 0, 0, 0);
                acc_o[ht + 1] = __builtin_amdgcn_mfma_f32_16x16x32_bf16(pa, bv1, acc_o[ht + 1], 0, 0, 0);
                acc_o[ht + 2] = __builtin_amdgcn_mfma_f32_16x16x32_bf16(pa, bv2, acc_o[ht + 2], 0, 0, 0);
                acc_o[ht + 3] = __builtin_amdgcn_mfma_f32_16x16x32_bf16(pa, bv3, acc_o[ht + 3], 0, 0, 0);
                __builtin_amdgcn_s_setprio(0);
            }
        }
    }

    #pragma unroll
    for (int r = 0; r < 4; ++r) {
        const float lr = __shfl(lreg, (l & 48) | (lg4 + r), 64);
        const float invl = 1.f / lr;
        const size_t row = (size_t)(b * S_ + sb * 64 + w * 16 + lg4 + r);
        #pragma unroll
        for (int ht = 0; ht < 8; ++ht)
            ao[(row * QH_ + qh) * HD_ + ht * 16 + lm] = f2bf(acc_o[ht][r] * invl);
    }
}

// ---------------------------------------------------------------------------
extern "C" void kernel_launch(void* const* d_in, const int* in_sizes, int n_in,
                              void* d_out, int out_size, void* d_ws, size_t ws_size,
                              hipStream_t stream)
{
    const float* x  = (const float*)d_in[0];
    const int*  pos = (const int*)d_in[1];
    const float* Wq = (const float*)d_in[2];
    const float* Wk = (const float*)d_in[3];
    const float* Wv = (const float*)d_in[4];
    const float* Wo = (const float*)d_in[5];
    float* out = (float*)d_out;

    char* wsb = (char*)d_ws;
    unsigned short* qkv = (unsigned short*)(wsb);              // 48 MiB [4096][6144]
    unsigned short* wt  = (unsigned short*)(wsb + 50331648);   // Wt_qkv 48M -> Wt_o 32M
    unsigned short* vt  = (unsigned short*)(wsb + 83886080);   // 8 MiB V^T
    unsigned short* r0  = (unsigned short*)(wsb + 100663296);  // 32 MiB x_bf -> ao

    const dim3 blk(256);
    const dim3 blk512(512);
    convert_bf16_kernel<<<8192, blk, 0, stream>>>(x, r0);
    transpose_conv_kernel<<<dim3(2, 64, 32), blk, 0, stream>>>(Wq, wt, D_, HD_);
    transpose_conv_kernel<<<dim3(2, 64, 8),  blk, 0, stream>>>(Wk, wt + (size_t)KOFF * D_, D_, HD_);
    transpose_conv_kernel<<<dim3(2, 64, 8),  blk, 0, stream>>>(Wv, wt + (size_t)VOFF * D_, D_, HD_);
    gemm256_kernel<0><<<dim3(NQKV / 256, MROWS / 256), blk512, 0, stream>>>(r0, wt, qkv, NQKV, D_);
    transpose_conv_kernel<<<dim3(64, 64, 1), blk, 0, stream>>>(Wo, wt, D_, D_);
    transpose_v_kernel<<<dim3(2, 32, 16), blk, 0, stream>>>(qkv, vt);
    rope_kernel<5><<<(MROWS * QH_ * 64) / 256, blk, 0, stream>>>(qkv, pos);
    rope_kernel<3><<<(MROWS * NH_ * 64) / 256, blk, 0, stream>>>(qkv + KOFF, pos);
    attn_kernel<<<B_ * QH_ * (S_ / 64), blk, 0, stream>>>(qkv, vt, r0);
    gemm256_kernel<1><<<dim3(D_ / 256, MROWS / 256), blk512, 0, stream>>>(r0, wt, out, D_, QH_ * HD_);
}